// Round 3
// baseline (4505.519 us; speedup 1.0000x reference)
//
#include <hip/hip_runtime.h>
#include <hip/hip_bf16.h>
#include <math.h>

#define N_NODES 50000
#define N_EDGES 800000

// ---- degree / normalization ------------------------------------------------
__global__ __launch_bounds__(256) void k_deg(const int* __restrict__ dst,
                                             float* __restrict__ deg) {
    int e = blockIdx.x * 256 + threadIdx.x;
    if (e < N_EDGES) atomicAdd(&deg[dst[e]], 1.0f);
}

__global__ __launch_bounds__(256) void k_dinv(float* deg) {
    int i = blockIdx.x * 256 + threadIdx.x;
    if (i < N_NODES) deg[i] = rsqrtf(deg[i] + 2.0f);  // improved: +2 self loop
}

// ---- dense transform: hs = (in @ W) * dinv[row],  F_out = 128 --------------
// block = 256 threads, 32 rows/block; W (128x128) + A-tile (32x128) in LDS.
__global__ __launch_bounds__(256) void k_gemm128(const float* __restrict__ in,
                                                 const float* __restrict__ W,
                                                 const float* __restrict__ dinv,
                                                 float* __restrict__ hs) {
    __shared__ float Wl[128 * 128];
    __shared__ float Al[32 * 128];
    const int tid = threadIdx.x;
    const int rbase = blockIdx.x * 32;
    for (int i = tid; i < 128 * 128; i += 256) Wl[i] = W[i];
    const int rlim = min(32, N_NODES - rbase);
    for (int i = tid; i < rlim * 128; i += 256)
        Al[i] = in[(size_t)rbase * 128 + i];
    __syncthreads();

    const int c0 = (tid & 31) * 4;
    const int r0 = (tid >> 5) * 4;
    float acc[4][4] = {{0.f}};
    for (int k0 = 0; k0 < 128; k0 += 4) {
        float4 w0 = *(const float4*)&Wl[(k0 + 0) * 128 + c0];
        float4 w1 = *(const float4*)&Wl[(k0 + 1) * 128 + c0];
        float4 w2 = *(const float4*)&Wl[(k0 + 2) * 128 + c0];
        float4 w3 = *(const float4*)&Wl[(k0 + 3) * 128 + c0];
#pragma unroll
        for (int r = 0; r < 4; ++r) {
            float4 a = *(const float4*)&Al[(r0 + r) * 128 + k0];
            acc[r][0] += a.x * w0.x + a.y * w1.x + a.z * w2.x + a.w * w3.x;
            acc[r][1] += a.x * w0.y + a.y * w1.y + a.z * w2.y + a.w * w3.y;
            acc[r][2] += a.x * w0.z + a.y * w1.z + a.z * w2.z + a.w * w3.z;
            acc[r][3] += a.x * w0.w + a.y * w1.w + a.z * w2.w + a.w * w3.w;
        }
    }
#pragma unroll
    for (int r = 0; r < 4; ++r) {
        int rr = r0 + r;
        if (rr < rlim) {
            float dv = dinv[rbase + rr];
            float4 o = make_float4(acc[r][0] * dv, acc[r][1] * dv,
                                   acc[r][2] * dv, acc[r][3] * dv);
            *(float4*)&hs[(size_t)(rbase + rr) * 128 + c0] = o;
        }
    }
}

// ---- dense transform, F_out = 16 (last layer) ------------------------------
__global__ __launch_bounds__(256) void k_gemm16(const float* __restrict__ in,
                                                const float* __restrict__ W,
                                                const float* __restrict__ dinv,
                                                float* __restrict__ hs) {
    __shared__ float Wt[16 * 132];  // [c][k], pad to break bank conflicts
    const int tid = threadIdx.x;
    for (int i = tid; i < 128 * 16; i += 256) {
        int k = i >> 4, c = i & 15;
        Wt[c * 132 + k] = W[i];
    }
    __syncthreads();
    int gid = blockIdx.x * 256 + tid;  // grid exactly 50000*16
    int r = gid >> 4, c = gid & 15;
    const float* arow = &in[(size_t)r * 128];
    const float* wrow = &Wt[c * 132];
    float acc = 0.f;
#pragma unroll
    for (int k0 = 0; k0 < 128; k0 += 4) {
        float4 a = *(const float4*)&arow[k0];
        float4 w = *(const float4*)&wrow[k0];
        acc += a.x * w.x + a.y * w.y + a.z * w.z + a.w * w.w;
    }
    hs[gid] = acc * dinv[r];
}

// ---- edge scatter: agg[dst] += hs[src]  (norm already folded into hs) ------
template <int LOGC>
__global__ __launch_bounds__(256) void k_scatter(const int* __restrict__ src,
                                                 const int* __restrict__ dst,
                                                 const float* __restrict__ hs,
                                                 float* __restrict__ agg) {
    int tid = blockIdx.x * 256 + threadIdx.x;  // grid sized exactly
    int e = tid >> LOGC;
    int f = (tid & ((1 << LOGC) - 1)) * 4;
    int s = src[e], d = dst[e];
    const int F = 4 << LOGC;
    float4 v = *(const float4*)&hs[(size_t)s * F + f];
    float* a = &agg[(size_t)d * F + f];
    atomicAdd(a + 0, v.x);
    atomicAdd(a + 1, v.y);
    atomicAdd(a + 2, v.z);
    atomicAdd(a + 3, v.w);
}

// ---- epilogue: out = act(dinv*(agg + 2*hs) + b) ----------------------------
template <int LOGC, bool TANH>
__global__ __launch_bounds__(256) void k_finalize(const float* __restrict__ agg,
                                                  const float* __restrict__ hs,
                                                  const float* __restrict__ dinv,
                                                  const float* __restrict__ bias,
                                                  float* __restrict__ out) {
    int i4 = blockIdx.x * 256 + threadIdx.x;  // float4-granular index
    int r = i4 >> LOGC;
    if (r >= N_NODES) return;
    int f = (i4 & ((1 << LOGC) - 1)) * 4;
    float dv = dinv[r];
    const float4 g = *(const float4*)&agg[(size_t)i4 * 4];
    const float4 h = *(const float4*)&hs[(size_t)i4 * 4];
    float v[4];
    v[0] = dv * (g.x + 2.f * h.x) + bias[f + 0];
    v[1] = dv * (g.y + 2.f * h.y) + bias[f + 1];
    v[2] = dv * (g.z + 2.f * h.z) + bias[f + 2];
    v[3] = dv * (g.w + 2.f * h.w) + bias[f + 3];
#pragma unroll
    for (int j = 0; j < 4; ++j) v[j] = TANH ? tanhf(v[j]) : fmaxf(v[j], 0.f);
    *(float4*)&out[(size_t)i4 * 4] = make_float4(v[0], v[1], v[2], v[3]);
}

extern "C" void kernel_launch(void* const* d_in, const int* in_sizes, int n_in,
                              void* d_out, int out_size, void* d_ws, size_t ws_size,
                              hipStream_t stream) {
    const float* x  = (const float*)d_in[0];
    const int* ei   = (const int*)d_in[1];
    const float* W0 = (const float*)d_in[2];
    const float* b0 = (const float*)d_in[3];
    const float* W1 = (const float*)d_in[4];
    const float* b1 = (const float*)d_in[5];
    const float* W2 = (const float*)d_in[6];
    const float* b2 = (const float*)d_in[7];
    const float* W3 = (const float*)d_in[8];
    const float* b3 = (const float*)d_in[9];
    const int* src = ei;
    const int* dst = ei + N_EDGES;

    // ws layout: A (act/agg, 50000x128 f32) | H (hs, 50000x128 f32) | dinv
    float* A    = (float*)d_ws;
    float* H    = A + (size_t)N_NODES * 128;
    float* dinv = H + (size_t)N_NODES * 128;

    (void)hipMemsetAsync(dinv, 0, N_NODES * sizeof(float), stream);
    k_deg<<<(N_EDGES + 255) / 256, 256, 0, stream>>>(dst, dinv);
    k_dinv<<<(N_NODES + 255) / 256, 256, 0, stream>>>(dinv);

    const size_t big = (size_t)N_NODES * 128 * sizeof(float);

    // ---- layer 0 ----
    k_gemm128<<<(N_NODES + 31) / 32, 256, 0, stream>>>(x, W0, dinv, H);
    (void)hipMemsetAsync(A, 0, big, stream);
    k_scatter<5><<<N_EDGES * 32 / 256, 256, 0, stream>>>(src, dst, H, A);
    k_finalize<5, false><<<N_NODES * 32 / 256, 256, 0, stream>>>(A, H, dinv, b0, A);

    // ---- layer 1 ----
    k_gemm128<<<(N_NODES + 31) / 32, 256, 0, stream>>>(A, W1, dinv, H);
    (void)hipMemsetAsync(A, 0, big, stream);
    k_scatter<5><<<N_EDGES * 32 / 256, 256, 0, stream>>>(src, dst, H, A);
    k_finalize<5, false><<<N_NODES * 32 / 256, 256, 0, stream>>>(A, H, dinv, b1, A);

    // ---- layer 2 ----
    k_gemm128<<<(N_NODES + 31) / 32, 256, 0, stream>>>(A, W2, dinv, H);
    (void)hipMemsetAsync(A, 0, big, stream);
    k_scatter<5><<<N_EDGES * 32 / 256, 256, 0, stream>>>(src, dst, H, A);
    k_finalize<5, false><<<N_NODES * 32 / 256, 256, 0, stream>>>(A, H, dinv, b2, A);

    // ---- layer 3 (128 -> 16, tanh) ----
    k_gemm16<<<N_NODES * 16 / 256, 256, 0, stream>>>(A, W3, dinv, H);
    (void)hipMemsetAsync(A, 0, (size_t)N_NODES * 16 * sizeof(float), stream);
    k_scatter<2><<<N_EDGES * 4 / 256, 256, 0, stream>>>(src, dst, H, A);
    k_finalize<2, true><<<(N_NODES * 4 + 255) / 256, 256, 0, stream>>>(
        A, H, dinv, b3, (float*)d_out);
}

// Round 4
// 551.895 us; speedup vs baseline: 8.1637x; 8.1637x over previous
//
#include <hip/hip_runtime.h>
#include <math.h>

#define N_NODES 50000
#define N_EDGES 800000

// ================= CSR build (by dst) =================
__global__ __launch_bounds__(256) void k_hist(const int* __restrict__ dst,
                                              int* __restrict__ cnt) {
    int e = blockIdx.x * 256 + threadIdx.x;
    if (e < N_EDGES) atomicAdd(&cnt[dst[e]], 1);
}

// single-block exclusive scan of cnt[0..N_NODES) -> off, off[N_NODES]=E
__global__ __launch_bounds__(1024) void k_scan(const int* __restrict__ cnt,
                                               int* __restrict__ off) {
    __shared__ int ls[1024];
    const int t = threadIdx.x;
    const int CH = (N_NODES + 1023) / 1024;  // 49
    int beg = t * CH, end = min(beg + CH, N_NODES);
    int s = 0;
    for (int i = beg; i < end; ++i) s += cnt[i];
    ls[t] = s;
    __syncthreads();
    for (int d = 1; d < 1024; d <<= 1) {
        int v = (t >= d) ? ls[t - d] : 0;
        __syncthreads();
        ls[t] += v;
        __syncthreads();
    }
    int run = (t > 0) ? ls[t - 1] : 0;
    for (int i = beg; i < end; ++i) { off[i] = run; run += cnt[i]; }
    if (t == 0) off[N_NODES] = ls[1023];
}

__global__ __launch_bounds__(256) void k_dinv(const int* __restrict__ cnt,
                                              float* __restrict__ dinv) {
    int i = blockIdx.x * 256 + threadIdx.x;
    if (i < N_NODES) dinv[i] = rsqrtf((float)cnt[i] + 2.0f);  // improved: +2
}

__global__ __launch_bounds__(256) void k_fill(const int* __restrict__ src,
                                              const int* __restrict__ dst,
                                              const int* __restrict__ off,
                                              int* __restrict__ cur,
                                              int* __restrict__ eidx) {
    int e = blockIdx.x * 256 + threadIdx.x;
    if (e >= N_EDGES) return;
    int d = dst[e];
    int pos = off[d] + atomicAdd(&cur[d], 1);
    eidx[pos] = src[e];
}

// ================= dense transform: hs = (in @ W) * dinv[row] ==============
__global__ __launch_bounds__(256) void k_gemm128(const float* __restrict__ in,
                                                 const float* __restrict__ W,
                                                 const float* __restrict__ dinv,
                                                 float* __restrict__ hs) {
    __shared__ float Wl[128 * 128];
    __shared__ float Al[32 * 128];
    const int tid = threadIdx.x;
    const int rbase = blockIdx.x * 32;
    for (int i = tid; i < 128 * 128; i += 256) Wl[i] = W[i];
    const int rlim = min(32, N_NODES - rbase);
    for (int i = tid; i < rlim * 128; i += 256)
        Al[i] = in[(size_t)rbase * 128 + i];
    __syncthreads();

    const int c0 = (tid & 31) * 4;
    const int r0 = (tid >> 5) * 4;
    float acc[4][4] = {{0.f}};
    for (int k0 = 0; k0 < 128; k0 += 4) {
        float4 w0 = *(const float4*)&Wl[(k0 + 0) * 128 + c0];
        float4 w1 = *(const float4*)&Wl[(k0 + 1) * 128 + c0];
        float4 w2 = *(const float4*)&Wl[(k0 + 2) * 128 + c0];
        float4 w3 = *(const float4*)&Wl[(k0 + 3) * 128 + c0];
#pragma unroll
        for (int r = 0; r < 4; ++r) {
            float4 a = *(const float4*)&Al[(r0 + r) * 128 + k0];
            acc[r][0] += a.x * w0.x + a.y * w1.x + a.z * w2.x + a.w * w3.x;
            acc[r][1] += a.x * w0.y + a.y * w1.y + a.z * w2.y + a.w * w3.y;
            acc[r][2] += a.x * w0.z + a.y * w1.z + a.z * w2.z + a.w * w3.z;
            acc[r][3] += a.x * w0.w + a.y * w1.w + a.z * w2.w + a.w * w3.w;
        }
    }
#pragma unroll
    for (int r = 0; r < 4; ++r) {
        int rr = r0 + r;
        if (rr < rlim) {
            float dv = dinv[rbase + rr];
            *(float4*)&hs[(size_t)(rbase + rr) * 128 + c0] =
                make_float4(acc[r][0] * dv, acc[r][1] * dv,
                            acc[r][2] * dv, acc[r][3] * dv);
        }
    }
}

__global__ __launch_bounds__(256) void k_gemm16(const float* __restrict__ in,
                                                const float* __restrict__ W,
                                                const float* __restrict__ dinv,
                                                float* __restrict__ hs) {
    __shared__ float Wt[16 * 132];
    const int tid = threadIdx.x;
    for (int i = tid; i < 128 * 16; i += 256) {
        int k = i >> 4, c = i & 15;
        Wt[c * 132 + k] = W[i];
    }
    __syncthreads();
    int gid = blockIdx.x * 256 + tid;  // grid exactly 50000*16
    int r = gid >> 4, c = gid & 15;
    const float* arow = &in[(size_t)r * 128];
    const float* wrow = &Wt[c * 132];
    float acc = 0.f;
#pragma unroll
    for (int k0 = 0; k0 < 128; k0 += 4) {
        float4 a = *(const float4*)&arow[k0];
        float4 w = *(const float4*)&wrow[k0];
        acc += a.x * w.x + a.y * w.y + a.z * w.z + a.w * w.w;
    }
    hs[gid] = acc * dinv[r];
}

// ====== fused aggregate + epilogue: out = act(dinv*(sum_in hs + 2hs) + b) ===
// 1<<LOGC lanes per node; lane owns float4 chunk. F = 4<<LOGC.
template <int LOGC, bool TANH>
__global__ __launch_bounds__(256) void k_gather(const int* __restrict__ off,
                                                const int* __restrict__ eidx,
                                                const float* __restrict__ hs,
                                                const float* __restrict__ dinv,
                                                const float* __restrict__ bias,
                                                float* __restrict__ out) {
    const int W = 1 << LOGC;
    const int F = 4 * W;
    int tid = blockIdx.x * 256 + threadIdx.x;
    int r = tid >> LOGC;
    if (r >= N_NODES) return;
    int l = tid & (W - 1);
    int f = l * 4;
    float4 h = *(const float4*)&hs[(size_t)r * F + f];
    float ax = 2.f * h.x, ay = 2.f * h.y, az = 2.f * h.z, aw = 2.f * h.w;
    int beg = off[r], end = off[r + 1];
    for (int i = beg; i < end; i += W) {
        int n = end - i;
        if (n > W) n = W;
        int my = (l < n) ? eidx[i + l] : 0;
        for (int j = 0; j < n; ++j) {
            int s = __shfl(my, j, W);
            float4 v = *(const float4*)&hs[(size_t)s * F + f];
            ax += v.x; ay += v.y; az += v.z; aw += v.w;
        }
    }
    float dv = dinv[r];
    float v0 = dv * ax + bias[f + 0];
    float v1 = dv * ay + bias[f + 1];
    float v2 = dv * az + bias[f + 2];
    float v3 = dv * aw + bias[f + 3];
    if (TANH) {
        v0 = tanhf(v0); v1 = tanhf(v1); v2 = tanhf(v2); v3 = tanhf(v3);
    } else {
        v0 = fmaxf(v0, 0.f); v1 = fmaxf(v1, 0.f);
        v2 = fmaxf(v2, 0.f); v3 = fmaxf(v3, 0.f);
    }
    *(float4*)&out[(size_t)r * F + f] = make_float4(v0, v1, v2, v3);
}

extern "C" void kernel_launch(void* const* d_in, const int* in_sizes, int n_in,
                              void* d_out, int out_size, void* d_ws, size_t ws_size,
                              hipStream_t stream) {
    const float* x  = (const float*)d_in[0];
    const int* ei   = (const int*)d_in[1];
    const float* W0 = (const float*)d_in[2];
    const float* b0 = (const float*)d_in[3];
    const float* W1 = (const float*)d_in[4];
    const float* b1 = (const float*)d_in[5];
    const float* W2 = (const float*)d_in[6];
    const float* b2 = (const float*)d_in[7];
    const float* W3 = (const float*)d_in[8];
    const float* b3 = (const float*)d_in[9];
    const int* src = ei;
    const int* dst = ei + N_EDGES;

    // ws layout (all 16B-aligned):
    float* A    = (float*)d_ws;                       // 50000*128
    float* H    = A + (size_t)N_NODES * 128;          // 50000*128
    float* dinv = H + (size_t)N_NODES * 128;          // 50000
    int* cnt    = (int*)(dinv + N_NODES);             // 50000
    int* off    = cnt + N_NODES;                      // 50016 (padded)
    int* cur    = off + 50016;                        // 50000
    int* eidx   = cur + N_NODES;                      // 800000

    // ---- CSR build (every call; ws is re-poisoned) ----
    (void)hipMemsetAsync(cnt, 0, N_NODES * sizeof(int), stream);
    (void)hipMemsetAsync(cur, 0, N_NODES * sizeof(int), stream);
    k_hist<<<(N_EDGES + 255) / 256, 256, 0, stream>>>(dst, cnt);
    k_scan<<<1, 1024, 0, stream>>>(cnt, off);
    k_dinv<<<(N_NODES + 255) / 256, 256, 0, stream>>>(cnt, dinv);
    k_fill<<<(N_EDGES + 255) / 256, 256, 0, stream>>>(src, dst, off, cur, eidx);

    // ---- layer 0 ----
    k_gemm128<<<(N_NODES + 31) / 32, 256, 0, stream>>>(x, W0, dinv, H);
    k_gather<5, false><<<N_NODES * 32 / 256, 256, 0, stream>>>(off, eidx, H, dinv, b0, A);
    // ---- layer 1 ----
    k_gemm128<<<(N_NODES + 31) / 32, 256, 0, stream>>>(A, W1, dinv, H);
    k_gather<5, false><<<N_NODES * 32 / 256, 256, 0, stream>>>(off, eidx, H, dinv, b1, A);
    // ---- layer 2 ----
    k_gemm128<<<(N_NODES + 31) / 32, 256, 0, stream>>>(A, W2, dinv, H);
    k_gather<5, false><<<N_NODES * 32 / 256, 256, 0, stream>>>(off, eidx, H, dinv, b2, A);
    // ---- layer 3 (128 -> 16, tanh) ----
    k_gemm16<<<N_NODES * 16 / 256, 256, 0, stream>>>(A, W3, dinv, H);
    k_gather<2, true><<<(N_NODES * 4 + 255) / 256, 256, 0, stream>>>(
        off, eidx, H, dinv, b3, (float*)d_out);
}

// Round 5
// 485.893 us; speedup vs baseline: 9.2726x; 1.1358x over previous
//
#include <hip/hip_runtime.h>
#include <math.h>

#define N_NODES 50000
#define N_EDGES 800000
#define SCAN_BLOCKS 196  // ceil(50000/256)

// ================= CSR build (by dst) =================
__global__ __launch_bounds__(256) void k_hist(const int* __restrict__ dst,
                                              int* __restrict__ cnt) {
    int e = blockIdx.x * 256 + threadIdx.x;
    if (e < N_EDGES) atomicAdd(&cnt[dst[e]], 1);
}

// Phase A: per-block sums of cnt (256-chunks)
__global__ __launch_bounds__(256) void k_scan_a(const int* __restrict__ cnt,
                                                int* __restrict__ bsum) {
    __shared__ int ls[256];
    int t = threadIdx.x;
    int i = blockIdx.x * 256 + t;
    ls[t] = (i < N_NODES) ? cnt[i] : 0;
    __syncthreads();
    for (int d = 128; d > 0; d >>= 1) {
        if (t < d) ls[t] += ls[t + d];
        __syncthreads();
    }
    if (t == 0) bsum[blockIdx.x] = ls[0];
}

// Phase B: exclusive scan of the block sums (single small block)
__global__ __launch_bounds__(256) void k_scan_b(const int* __restrict__ bsum,
                                                int* __restrict__ boff,
                                                int* __restrict__ off) {
    __shared__ int ls[256];
    int t = threadIdx.x;
    int v = (t < SCAN_BLOCKS) ? bsum[t] : 0;
    ls[t] = v;
    __syncthreads();
    for (int d = 1; d < 256; d <<= 1) {
        int u = (t >= d) ? ls[t - d] : 0;
        __syncthreads();
        ls[t] += u;
        __syncthreads();
    }
    if (t < SCAN_BLOCKS) boff[t] = ls[t] - v;  // exclusive
    if (t == 0) off[N_NODES] = N_EDGES;
}

// Phase C: in-block exclusive scan + block offset -> off; fused dinv
__global__ __launch_bounds__(256) void k_scan_c(const int* __restrict__ cnt,
                                                const int* __restrict__ boff,
                                                int* __restrict__ off,
                                                float* __restrict__ dinv) {
    __shared__ int ls[256];
    int t = threadIdx.x;
    int i = blockIdx.x * 256 + t;
    int v = (i < N_NODES) ? cnt[i] : 0;
    ls[t] = v;
    __syncthreads();
    for (int d = 1; d < 256; d <<= 1) {
        int u = (t >= d) ? ls[t - d] : 0;
        __syncthreads();
        ls[t] += u;
        __syncthreads();
    }
    if (i < N_NODES) {
        off[i] = boff[blockIdx.x] + ls[t] - v;       // exclusive
        dinv[i] = rsqrtf((float)v + 2.0f);            // improved: +2 self loop
    }
}

__global__ __launch_bounds__(256) void k_fill(const int* __restrict__ src,
                                              const int* __restrict__ dst,
                                              const int* __restrict__ off,
                                              int* __restrict__ cur,
                                              int* __restrict__ eidx) {
    int e = blockIdx.x * 256 + threadIdx.x;
    if (e >= N_EDGES) return;
    int d = dst[e];
    int pos = off[d] + atomicAdd(&cur[d], 1);
    eidx[pos] = src[e];
}

// ================= dense transform: hs = (in @ W) * dinv[row] ==============
__global__ __launch_bounds__(256) void k_gemm128(const float* __restrict__ in,
                                                 const float* __restrict__ W,
                                                 const float* __restrict__ dinv,
                                                 float* __restrict__ hs) {
    __shared__ float Wl[128 * 128];
    __shared__ float Al[32 * 128];
    const int tid = threadIdx.x;
    const int rbase = blockIdx.x * 32;
    for (int i = tid; i < 128 * 128; i += 256) Wl[i] = W[i];
    const int rlim = min(32, N_NODES - rbase);
    for (int i = tid; i < rlim * 128; i += 256)
        Al[i] = in[(size_t)rbase * 128 + i];
    __syncthreads();

    const int c0 = (tid & 31) * 4;
    const int r0 = (tid >> 5) * 4;
    float acc[4][4] = {{0.f}};
    for (int k0 = 0; k0 < 128; k0 += 4) {
        float4 w0 = *(const float4*)&Wl[(k0 + 0) * 128 + c0];
        float4 w1 = *(const float4*)&Wl[(k0 + 1) * 128 + c0];
        float4 w2 = *(const float4*)&Wl[(k0 + 2) * 128 + c0];
        float4 w3 = *(const float4*)&Wl[(k0 + 3) * 128 + c0];
#pragma unroll
        for (int r = 0; r < 4; ++r) {
            float4 a = *(const float4*)&Al[(r0 + r) * 128 + k0];
            acc[r][0] += a.x * w0.x + a.y * w1.x + a.z * w2.x + a.w * w3.x;
            acc[r][1] += a.x * w0.y + a.y * w1.y + a.z * w2.y + a.w * w3.y;
            acc[r][2] += a.x * w0.z + a.y * w1.z + a.z * w2.z + a.w * w3.z;
            acc[r][3] += a.x * w0.w + a.y * w1.w + a.z * w2.w + a.w * w3.w;
        }
    }
#pragma unroll
    for (int r = 0; r < 4; ++r) {
        int rr = r0 + r;
        if (rr < rlim) {
            float dv = dinv[rbase + rr];
            *(float4*)&hs[(size_t)(rbase + rr) * 128 + c0] =
                make_float4(acc[r][0] * dv, acc[r][1] * dv,
                            acc[r][2] * dv, acc[r][3] * dv);
        }
    }
}

__global__ __launch_bounds__(256) void k_gemm16(const float* __restrict__ in,
                                                const float* __restrict__ W,
                                                const float* __restrict__ dinv,
                                                float* __restrict__ hs) {
    __shared__ float Wt[16 * 132];
    const int tid = threadIdx.x;
    for (int i = tid; i < 128 * 16; i += 256) {
        int k = i >> 4, c = i & 15;
        Wt[c * 132 + k] = W[i];
    }
    __syncthreads();
    int gid = blockIdx.x * 256 + tid;  // grid exactly 50000*16
    int r = gid >> 4, c = gid & 15;
    const float* arow = &in[(size_t)r * 128];
    const float* wrow = &Wt[c * 132];
    float acc = 0.f;
#pragma unroll
    for (int k0 = 0; k0 < 128; k0 += 4) {
        float4 a = *(const float4*)&arow[k0];
        float4 w = *(const float4*)&wrow[k0];
        acc += a.x * w.x + a.y * w.y + a.z * w.z + a.w * w.w;
    }
    hs[gid] = acc * dinv[r];
}

// ====== fused aggregate + epilogue: out = act(dinv*(sum_in hs + 2hs) + b) ===
// 1<<LOGC lanes per node; lane owns float4 chunk. F = 4<<LOGC.
template <int LOGC, bool TANH>
__global__ __launch_bounds__(256) void k_gather(const int* __restrict__ off,
                                                const int* __restrict__ eidx,
                                                const float* __restrict__ hs,
                                                const float* __restrict__ dinv,
                                                const float* __restrict__ bias,
                                                float* __restrict__ out) {
    const int W = 1 << LOGC;
    const int F = 4 * W;
    int tid = blockIdx.x * 256 + threadIdx.x;
    int r = tid >> LOGC;
    if (r >= N_NODES) return;
    int l = tid & (W - 1);
    int f = l * 4;
    float4 h = *(const float4*)&hs[(size_t)r * F + f];
    float ax = 2.f * h.x, ay = 2.f * h.y, az = 2.f * h.z, aw = 2.f * h.w;
    int beg = off[r], end = off[r + 1];
    for (int i = beg; i < end; i += W) {
        int n = end - i;
        if (n > W) n = W;
        int my = (l < n) ? eidx[i + l] : 0;
        for (int j = 0; j < n; ++j) {
            int s = __shfl(my, j, W);
            float4 v = *(const float4*)&hs[(size_t)s * F + f];
            ax += v.x; ay += v.y; az += v.z; aw += v.w;
        }
    }
    float dv = dinv[r];
    float v0 = dv * ax + bias[f + 0];
    float v1 = dv * ay + bias[f + 1];
    float v2 = dv * az + bias[f + 2];
    float v3 = dv * aw + bias[f + 3];
    if (TANH) {
        v0 = tanhf(v0); v1 = tanhf(v1); v2 = tanhf(v2); v3 = tanhf(v3);
    } else {
        v0 = fmaxf(v0, 0.f); v1 = fmaxf(v1, 0.f);
        v2 = fmaxf(v2, 0.f); v3 = fmaxf(v3, 0.f);
    }
    *(float4*)&out[(size_t)r * F + f] = make_float4(v0, v1, v2, v3);
}

extern "C" void kernel_launch(void* const* d_in, const int* in_sizes, int n_in,
                              void* d_out, int out_size, void* d_ws, size_t ws_size,
                              hipStream_t stream) {
    const float* x  = (const float*)d_in[0];
    const int* ei   = (const int*)d_in[1];
    const float* W0 = (const float*)d_in[2];
    const float* b0 = (const float*)d_in[3];
    const float* W1 = (const float*)d_in[4];
    const float* b1 = (const float*)d_in[5];
    const float* W2 = (const float*)d_in[6];
    const float* b2 = (const float*)d_in[7];
    const float* W3 = (const float*)d_in[8];
    const float* b3 = (const float*)d_in[9];
    const int* src = ei;
    const int* dst = ei + N_EDGES;

    // ws layout (all 16B-aligned); cnt+cur adjacent -> single memset
    float* A    = (float*)d_ws;                       // 50000*128
    float* H    = A + (size_t)N_NODES * 128;          // 50000*128
    float* dinv = H + (size_t)N_NODES * 128;          // 50000
    int* cnt    = (int*)(dinv + N_NODES);             // 50000
    int* cur    = cnt + N_NODES;                      // 50000
    int* off    = cur + N_NODES;                      // 50016 (padded)
    int* eidx   = off + 50016;                        // 800000
    int* bsum   = eidx + N_EDGES;                     // 256
    int* boff   = bsum + 256;                         // 256

    // ---- CSR build (every call; ws is re-poisoned) ----
    (void)hipMemsetAsync(cnt, 0, 2 * N_NODES * sizeof(int), stream);  // cnt+cur
    k_hist<<<(N_EDGES + 255) / 256, 256, 0, stream>>>(dst, cnt);
    k_scan_a<<<SCAN_BLOCKS, 256, 0, stream>>>(cnt, bsum);
    k_scan_b<<<1, 256, 0, stream>>>(bsum, boff, off);
    k_scan_c<<<SCAN_BLOCKS, 256, 0, stream>>>(cnt, boff, off, dinv);
    k_fill<<<(N_EDGES + 255) / 256, 256, 0, stream>>>(src, dst, off, cur, eidx);

    // ---- layer 0 ----
    k_gemm128<<<(N_NODES + 31) / 32, 256, 0, stream>>>(x, W0, dinv, H);
    k_gather<5, false><<<N_NODES * 32 / 256, 256, 0, stream>>>(off, eidx, H, dinv, b0, A);
    // ---- layer 1 ----
    k_gemm128<<<(N_NODES + 31) / 32, 256, 0, stream>>>(A, W1, dinv, H);
    k_gather<5, false><<<N_NODES * 32 / 256, 256, 0, stream>>>(off, eidx, H, dinv, b1, A);
    // ---- layer 2 ----
    k_gemm128<<<(N_NODES + 31) / 32, 256, 0, stream>>>(A, W2, dinv, H);
    k_gather<5, false><<<N_NODES * 32 / 256, 256, 0, stream>>>(off, eidx, H, dinv, b2, A);
    // ---- layer 3 (128 -> 16, tanh) ----
    k_gemm16<<<N_NODES * 16 / 256, 256, 0, stream>>>(A, W3, dinv, H);
    k_gather<2, true><<<(N_NODES * 4 + 255) / 256, 256, 0, stream>>>(
        off, eidx, H, dinv, b3, (float*)d_out);
}

// Round 6
// 429.882 us; speedup vs baseline: 10.4808x; 1.1303x over previous
//
#include <hip/hip_runtime.h>
#include <hip/hip_fp16.h>
#include <math.h>

#define N_NODES 50000
#define N_EDGES 800000
#define SCAN_BLOCKS 196  // ceil(50000/256)

// ================= CSR build (by dst) =================
__global__ __launch_bounds__(256) void k_hist(const int* __restrict__ dst,
                                              int* __restrict__ cnt) {
    int e = blockIdx.x * 256 + threadIdx.x;
    if (e < N_EDGES) atomicAdd(&cnt[dst[e]], 1);
}

__global__ __launch_bounds__(256) void k_scan_a(const int* __restrict__ cnt,
                                                int* __restrict__ bsum) {
    __shared__ int ls[256];
    int t = threadIdx.x;
    int i = blockIdx.x * 256 + t;
    ls[t] = (i < N_NODES) ? cnt[i] : 0;
    __syncthreads();
    for (int d = 128; d > 0; d >>= 1) {
        if (t < d) ls[t] += ls[t + d];
        __syncthreads();
    }
    if (t == 0) bsum[blockIdx.x] = ls[0];
}

__global__ __launch_bounds__(256) void k_scan_b(const int* __restrict__ bsum,
                                                int* __restrict__ boff,
                                                int* __restrict__ off) {
    __shared__ int ls[256];
    int t = threadIdx.x;
    int v = (t < SCAN_BLOCKS) ? bsum[t] : 0;
    ls[t] = v;
    __syncthreads();
    for (int d = 1; d < 256; d <<= 1) {
        int u = (t >= d) ? ls[t - d] : 0;
        __syncthreads();
        ls[t] += u;
        __syncthreads();
    }
    if (t < SCAN_BLOCKS) boff[t] = ls[t] - v;  // exclusive
    if (t == 0) off[N_NODES] = N_EDGES;
}

__global__ __launch_bounds__(256) void k_scan_c(const int* __restrict__ cnt,
                                                const int* __restrict__ boff,
                                                int* __restrict__ off,
                                                float* __restrict__ dinv) {
    __shared__ int ls[256];
    int t = threadIdx.x;
    int i = blockIdx.x * 256 + t;
    int v = (i < N_NODES) ? cnt[i] : 0;
    ls[t] = v;
    __syncthreads();
    for (int d = 1; d < 256; d <<= 1) {
        int u = (t >= d) ? ls[t - d] : 0;
        __syncthreads();
        ls[t] += u;
        __syncthreads();
    }
    if (i < N_NODES) {
        off[i] = boff[blockIdx.x] + ls[t] - v;  // exclusive
        dinv[i] = rsqrtf((float)v + 2.0f);      // improved: +2 self loop
    }
}

__global__ __launch_bounds__(256) void k_fill(const int* __restrict__ src,
                                              const int* __restrict__ dst,
                                              const int* __restrict__ off,
                                              int* __restrict__ cur,
                                              int* __restrict__ eidx) {
    int e = blockIdx.x * 256 + threadIdx.x;
    if (e >= N_EDGES) return;
    int d = dst[e];
    int pos = off[d] + atomicAdd(&cur[d], 1);
    eidx[pos] = src[e];
}

// ====== dense transform: hs = fp16((in @ W) * dinv[row]), F_out = 128 ======
// 128x128 block tile, K chunked by 32. 256 thr, 8x8 accumulator/thread.
// LDS: Al 128x33 (pad -> conflict-free), Wl 32x128. ~33 KB -> 4 blocks/CU.
__global__ __launch_bounds__(256) void k_gemm128(const float* __restrict__ in,
                                                 const float* __restrict__ W,
                                                 const float* __restrict__ dinv,
                                                 __half* __restrict__ hs) {
    __shared__ float Al[128 * 33];
    __shared__ float Wl[32 * 128];
    const int tid = threadIdx.x;
    const int rbase = blockIdx.x * 128;
    const int rlim = min(128, N_NODES - rbase);
    const int r0 = (tid >> 4) * 8;
    const int c0 = (tid & 15) * 8;
    float acc[8][8] = {{0.f}};

    for (int kc = 0; kc < 128; kc += 32) {
        __syncthreads();
        // stage A chunk [r][k], conflict-free scalar writes (bank = r+k)
        for (int i = tid; i < 128 * 32; i += 256) {
            int r = i >> 5, k = i & 31;
            Al[r * 33 + k] =
                (r < rlim) ? in[(size_t)(rbase + r) * 128 + kc + k] : 0.f;
        }
        // stage W chunk [k][c], vector copy
        for (int i = tid; i < 32 * 128 / 4; i += 256)
            *(float4*)&Wl[i * 4] = *(const float4*)&W[(size_t)kc * 128 + i * 4];
        __syncthreads();
#pragma unroll
        for (int k = 0; k < 32; ++k) {
            float4 w0 = *(const float4*)&Wl[k * 128 + c0];
            float4 w1 = *(const float4*)&Wl[k * 128 + c0 + 4];
            float w[8] = {w0.x, w0.y, w0.z, w0.w, w1.x, w1.y, w1.z, w1.w};
            float a[8];
#pragma unroll
            for (int j = 0; j < 8; ++j) a[j] = Al[(r0 + j) * 33 + k];
#pragma unroll
            for (int i = 0; i < 8; ++i)
#pragma unroll
                for (int j = 0; j < 8; ++j) acc[i][j] += a[i] * w[j];
        }
    }
#pragma unroll
    for (int i = 0; i < 8; ++i) {
        int rr = r0 + i;
        if (rr < rlim) {
            float dv = dinv[rbase + rr];
            union { uint4 u; __half2 h2[4]; } p;
#pragma unroll
            for (int q = 0; q < 4; ++q)
                p.h2[q] = __floats2half2_rn(acc[i][2 * q] * dv,
                                            acc[i][2 * q + 1] * dv);
            *(uint4*)&hs[(size_t)(rbase + rr) * 128 + c0] = p.u;
        }
    }
}

// ---- dense transform, F_out = 16 (last layer, fp32 H — tiny traffic) ------
__global__ __launch_bounds__(256) void k_gemm16(const float* __restrict__ in,
                                                const float* __restrict__ W,
                                                const float* __restrict__ dinv,
                                                float* __restrict__ hs) {
    __shared__ float Wt[16 * 132];
    const int tid = threadIdx.x;
    for (int i = tid; i < 128 * 16; i += 256) {
        int k = i >> 4, c = i & 15;
        Wt[c * 132 + k] = W[i];
    }
    __syncthreads();
    int gid = blockIdx.x * 256 + tid;  // grid exactly 50000*16
    int r = gid >> 4, c = gid & 15;
    const float* arow = &in[(size_t)r * 128];
    const float* wrow = &Wt[c * 132];
    float acc = 0.f;
#pragma unroll
    for (int k0 = 0; k0 < 128; k0 += 4) {
        float4 a = *(const float4*)&arow[k0];
        float4 w = *(const float4*)&wrow[k0];
        acc += a.x * w.x + a.y * w.y + a.z * w.z + a.w * w.w;
    }
    hs[gid] = acc * dinv[r];
}

// ====== fused aggregate + epilogue, fp16 H, F=128 ======
// 16 lanes/node; lane owns 8 halves (16 B). acc fp32.
template <bool TANH>
__global__ __launch_bounds__(256) void k_gather_h(const int* __restrict__ off,
                                                  const int* __restrict__ eidx,
                                                  const __half* __restrict__ hs,
                                                  const float* __restrict__ dinv,
                                                  const float* __restrict__ bias,
                                                  float* __restrict__ out) {
    int tid = blockIdx.x * 256 + threadIdx.x;
    int r = tid >> 4;
    if (r >= N_NODES) return;
    int l = tid & 15;
    int f = l * 8;
    float acc[8];
    {
        union { uint4 u; __half2 h2[4]; } p;
        p.u = *(const uint4*)&hs[(size_t)r * 128 + f];
#pragma unroll
        for (int q = 0; q < 4; ++q) {
            float2 v = __half22float2(p.h2[q]);
            acc[2 * q] = 2.f * v.x;
            acc[2 * q + 1] = 2.f * v.y;
        }
    }
    int beg = off[r], end = off[r + 1];
    for (int i = beg; i < end; i += 16) {
        int n = end - i;
        if (n > 16) n = 16;
        int my = (l < n) ? eidx[i + l] : 0;
        for (int j = 0; j < n; ++j) {
            int s = __shfl(my, j, 16);
            union { uint4 u; __half2 h2[4]; } p;
            p.u = *(const uint4*)&hs[(size_t)s * 128 + f];
#pragma unroll
            for (int q = 0; q < 4; ++q) {
                float2 v = __half22float2(p.h2[q]);
                acc[2 * q] += v.x;
                acc[2 * q + 1] += v.y;
            }
        }
    }
    float dv = dinv[r];
    float o[8];
#pragma unroll
    for (int j = 0; j < 8; ++j) {
        float v = dv * acc[j] + bias[f + j];
        o[j] = TANH ? tanhf(v) : fmaxf(v, 0.f);
    }
    *(float4*)&out[(size_t)r * 128 + f] = make_float4(o[0], o[1], o[2], o[3]);
    *(float4*)&out[(size_t)r * 128 + f + 4] = make_float4(o[4], o[5], o[6], o[7]);
}

// ====== fp32 gather for the last (F=16) layer ======
template <int LOGC, bool TANH>
__global__ __launch_bounds__(256) void k_gather(const int* __restrict__ off,
                                                const int* __restrict__ eidx,
                                                const float* __restrict__ hs,
                                                const float* __restrict__ dinv,
                                                const float* __restrict__ bias,
                                                float* __restrict__ out) {
    const int W = 1 << LOGC;
    const int F = 4 * W;
    int tid = blockIdx.x * 256 + threadIdx.x;
    int r = tid >> LOGC;
    if (r >= N_NODES) return;
    int l = tid & (W - 1);
    int f = l * 4;
    float4 h = *(const float4*)&hs[(size_t)r * F + f];
    float ax = 2.f * h.x, ay = 2.f * h.y, az = 2.f * h.z, aw = 2.f * h.w;
    int beg = off[r], end = off[r + 1];
    for (int i = beg; i < end; i += W) {
        int n = end - i;
        if (n > W) n = W;
        int my = (l < n) ? eidx[i + l] : 0;
        for (int j = 0; j < n; ++j) {
            int s = __shfl(my, j, W);
            float4 v = *(const float4*)&hs[(size_t)s * F + f];
            ax += v.x; ay += v.y; az += v.z; aw += v.w;
        }
    }
    float dv = dinv[r];
    float v0 = dv * ax + bias[f + 0];
    float v1 = dv * ay + bias[f + 1];
    float v2 = dv * az + bias[f + 2];
    float v3 = dv * aw + bias[f + 3];
    if (TANH) {
        v0 = tanhf(v0); v1 = tanhf(v1); v2 = tanhf(v2); v3 = tanhf(v3);
    } else {
        v0 = fmaxf(v0, 0.f); v1 = fmaxf(v1, 0.f);
        v2 = fmaxf(v2, 0.f); v3 = fmaxf(v3, 0.f);
    }
    *(float4*)&out[(size_t)r * F + f] = make_float4(v0, v1, v2, v3);
}

extern "C" void kernel_launch(void* const* d_in, const int* in_sizes, int n_in,
                              void* d_out, int out_size, void* d_ws, size_t ws_size,
                              hipStream_t stream) {
    const float* x  = (const float*)d_in[0];
    const int* ei   = (const int*)d_in[1];
    const float* W0 = (const float*)d_in[2];
    const float* b0 = (const float*)d_in[3];
    const float* W1 = (const float*)d_in[4];
    const float* b1 = (const float*)d_in[5];
    const float* W2 = (const float*)d_in[6];
    const float* b2 = (const float*)d_in[7];
    const float* W3 = (const float*)d_in[8];
    const float* b3 = (const float*)d_in[9];
    const int* src = ei;
    const int* dst = ei + N_EDGES;

    // ws layout (16B-aligned):
    float*  A    = (float*)d_ws;                      // 50000*128 f32
    __half* Hh   = (__half*)(A + (size_t)N_NODES * 128);  // 50000*128 f16
    float*  H16  = (float*)(Hh + (size_t)N_NODES * 128);  // 50000*16 f32
    float*  dinv = H16 + (size_t)N_NODES * 16;        // 50000
    int* cnt    = (int*)(dinv + N_NODES);             // 50000
    int* cur    = cnt + N_NODES;                      // 50000
    int* off    = cur + N_NODES;                      // 50016 (padded)
    int* eidx   = off + 50016;                        // 800000
    int* bsum   = eidx + N_EDGES;                     // 256
    int* boff   = bsum + 256;                         // 256

    // ---- CSR build (every call; ws is re-poisoned) ----
    (void)hipMemsetAsync(cnt, 0, 2 * N_NODES * sizeof(int), stream);  // cnt+cur
    k_hist<<<(N_EDGES + 255) / 256, 256, 0, stream>>>(dst, cnt);
    k_scan_a<<<SCAN_BLOCKS, 256, 0, stream>>>(cnt, bsum);
    k_scan_b<<<1, 256, 0, stream>>>(bsum, boff, off);
    k_scan_c<<<SCAN_BLOCKS, 256, 0, stream>>>(cnt, boff, off, dinv);
    k_fill<<<(N_EDGES + 255) / 256, 256, 0, stream>>>(src, dst, off, cur, eidx);

    const int GB = (N_NODES + 127) / 128;  // gemm128 blocks
    // ---- layer 0 ----
    k_gemm128<<<GB, 256, 0, stream>>>(x, W0, dinv, Hh);
    k_gather_h<false><<<N_NODES * 16 / 256, 256, 0, stream>>>(off, eidx, Hh, dinv, b0, A);
    // ---- layer 1 ----
    k_gemm128<<<GB, 256, 0, stream>>>(A, W1, dinv, Hh);
    k_gather_h<false><<<N_NODES * 16 / 256, 256, 0, stream>>>(off, eidx, Hh, dinv, b1, A);
    // ---- layer 2 ----
    k_gemm128<<<GB, 256, 0, stream>>>(A, W2, dinv, Hh);
    k_gather_h<false><<<N_NODES * 16 / 256, 256, 0, stream>>>(off, eidx, Hh, dinv, b2, A);
    // ---- layer 3 (128 -> 16, tanh) ----
    k_gemm16<<<N_NODES * 16 / 256, 256, 0, stream>>>(A, W3, dinv, H16);
    k_gather<2, true><<<(N_NODES * 4 + 255) / 256, 256, 0, stream>>>(
        off, eidx, H16, dinv, b3, (float*)d_out);
}

// Round 7
// 371.416 us; speedup vs baseline: 12.1307x; 1.1574x over previous
//
#include <hip/hip_runtime.h>
#include <hip/hip_fp16.h>
#include <math.h>

#define N_NODES 50000
#define N_EDGES 800000
#define SCAN_BLOCKS 196  // ceil(50000/256)

typedef _Float16 half8 __attribute__((ext_vector_type(8)));
typedef float floatx4 __attribute__((ext_vector_type(4)));

// ================= CSR build (by dst) =================
__global__ __launch_bounds__(256) void k_hist(const int* __restrict__ dst,
                                              int* __restrict__ cnt) {
    int e = blockIdx.x * 256 + threadIdx.x;
    if (e < N_EDGES) atomicAdd(&cnt[dst[e]], 1);
}

__global__ __launch_bounds__(256) void k_scan_a(const int* __restrict__ cnt,
                                                int* __restrict__ bsum) {
    __shared__ int ls[256];
    int t = threadIdx.x;
    int i = blockIdx.x * 256 + t;
    ls[t] = (i < N_NODES) ? cnt[i] : 0;
    __syncthreads();
    for (int d = 128; d > 0; d >>= 1) {
        if (t < d) ls[t] += ls[t + d];
        __syncthreads();
    }
    if (t == 0) bsum[blockIdx.x] = ls[0];
}

__global__ __launch_bounds__(256) void k_scan_b(const int* __restrict__ bsum,
                                                int* __restrict__ boff,
                                                int* __restrict__ off) {
    __shared__ int ls[256];
    int t = threadIdx.x;
    int v = (t < SCAN_BLOCKS) ? bsum[t] : 0;
    ls[t] = v;
    __syncthreads();
    for (int d = 1; d < 256; d <<= 1) {
        int u = (t >= d) ? ls[t - d] : 0;
        __syncthreads();
        ls[t] += u;
        __syncthreads();
    }
    if (t < SCAN_BLOCKS) boff[t] = ls[t] - v;  // exclusive
    if (t == 0) off[N_NODES] = N_EDGES;
}

__global__ __launch_bounds__(256) void k_scan_c(const int* __restrict__ cnt,
                                                const int* __restrict__ boff,
                                                int* __restrict__ off,
                                                float* __restrict__ dinv) {
    __shared__ int ls[256];
    int t = threadIdx.x;
    int i = blockIdx.x * 256 + t;
    int v = (i < N_NODES) ? cnt[i] : 0;
    ls[t] = v;
    __syncthreads();
    for (int d = 1; d < 256; d <<= 1) {
        int u = (t >= d) ? ls[t - d] : 0;
        __syncthreads();
        ls[t] += u;
        __syncthreads();
    }
    if (i < N_NODES) {
        off[i] = boff[blockIdx.x] + ls[t] - v;  // exclusive
        dinv[i] = rsqrtf((float)v + 2.0f);      // improved: +2 self loop
    }
}

__global__ __launch_bounds__(256) void k_fill(const int* __restrict__ src,
                                              const int* __restrict__ dst,
                                              const int* __restrict__ off,
                                              int* __restrict__ cur,
                                              int* __restrict__ eidx) {
    int e = blockIdx.x * 256 + threadIdx.x;
    if (e >= N_EDGES) return;
    int d = dst[e];
    int pos = off[d] + atomicAdd(&cur[d], 1);
    eidx[pos] = src[e];
}

// ---- x (fp32) -> fp16, vectorized ----
__global__ __launch_bounds__(256) void k_cast(const float* __restrict__ x,
                                              __half* __restrict__ xh) {
    int i = blockIdx.x * 256 + threadIdx.x;  // float4-granular; grid exact
    float4 v = *(const float4*)&x[(size_t)i * 4];
    union { ushort4 u; __half h[4]; } p;
    p.h[0] = __float2half(v.x); p.h[1] = __float2half(v.y);
    p.h[2] = __float2half(v.z); p.h[3] = __float2half(v.w);
    *(ushort4*)&xh[(size_t)i * 4] = p.u;
}

// ---- W (fp32 [k][n] 128x128) -> fp16 W^T [n][k] ----
__global__ __launch_bounds__(256) void k_prepw(const float* __restrict__ W,
                                               __half* __restrict__ WT) {
    int i = blockIdx.x * 256 + threadIdx.x;  // 16384 total, grid = 64
    int k = i >> 7, n = i & 127;
    WT[n * 128 + k] = __float2half(W[i]);
}

// ====== MFMA GEMM: hs = fp16((Ah @ W) * dinv[row]) via W^T fp16 ============
// Block = 4 waves; wave handles 16 rows x 128 cols; K=128 in 4 mfma steps.
// A-frag & B-frag are contiguous 16B loads (layout: elem k = quad*8+j).
// No LDS, no syncthreads, no bank conflicts.
__global__ __launch_bounds__(256) void k_gemm_mfma(const __half* __restrict__ Ah,
                                                   const __half* __restrict__ WT,
                                                   const float* __restrict__ dinv,
                                                   __half* __restrict__ hs) {
    const int tid = threadIdx.x;
    const int wave = tid >> 6;
    const int lane = tid & 63;
    const int m = lane & 15;
    const int quad = lane >> 4;
    const int rowA = blockIdx.x * 64 + wave * 16 + m;
    const int rA = (rowA < N_NODES) ? rowA : 0;  // clamp: garbage only lands
                                                 // in unsaved rows
    const __half* arow = Ah + (size_t)rA * 128 + quad * 8;

    floatx4 acc[8] = {};
#pragma unroll
    for (int kb = 0; kb < 4; ++kb) {
        half8 af = *(const half8*)(arow + kb * 32);
#pragma unroll
        for (int nt = 0; nt < 8; ++nt) {
            half8 bf = *(const half8*)(WT + (size_t)(nt * 16 + m) * 128 +
                                       kb * 32 + quad * 8);
            acc[nt] = __builtin_amdgcn_mfma_f32_16x16x32_f16(af, bf, acc[nt],
                                                             0, 0, 0);
        }
    }
    // C/D: col = lane&15 (=m), row = quad*4 + reg
    const int rb = blockIdx.x * 64 + wave * 16 + quad * 4;
#pragma unroll
    for (int r = 0; r < 4; ++r) {
        int row = rb + r;
        if (row < N_NODES) {
            float dv = dinv[row];
            __half* orow = hs + (size_t)row * 128 + m;
#pragma unroll
            for (int nt = 0; nt < 8; ++nt)
                orow[nt * 16] = __float2half(acc[nt][r] * dv);
        }
    }
}

// ---- dense transform, F_out = 16 (last layer): fp16 in, fp32 out ----------
__global__ __launch_bounds__(256) void k_gemm16(const __half* __restrict__ in,
                                                const float* __restrict__ W,
                                                const float* __restrict__ dinv,
                                                float* __restrict__ hs) {
    __shared__ float Wt[16 * 132];
    const int tid = threadIdx.x;
    for (int i = tid; i < 128 * 16; i += 256) {
        int k = i >> 4, c = i & 15;
        Wt[c * 132 + k] = W[i];
    }
    __syncthreads();
    int gid = blockIdx.x * 256 + tid;  // grid exactly 50000*16
    int r = gid >> 4, c = gid & 15;
    const __half* arow = &in[(size_t)r * 128];
    const float* wrow = &Wt[c * 132];
    float acc = 0.f;
#pragma unroll
    for (int k0 = 0; k0 < 128; k0 += 8) {
        union { uint4 u; __half2 h2[4]; } p;
        p.u = *(const uint4*)&arow[k0];
#pragma unroll
        for (int q = 0; q < 4; ++q) {
            float2 a = __half22float2(p.h2[q]);
            acc += a.x * wrow[k0 + 2 * q] + a.y * wrow[k0 + 2 * q + 1];
        }
    }
    hs[gid] = acc * dinv[r];
}

// ====== fused aggregate + epilogue, fp16 H, F=128, templated output ========
// 16 lanes/node; lane owns 8 halves (16 B). acc fp32.
__device__ __forceinline__ void store8(float* p, const float* o) {
    *(float4*)p = make_float4(o[0], o[1], o[2], o[3]);
    *(float4*)(p + 4) = make_float4(o[4], o[5], o[6], o[7]);
}
__device__ __forceinline__ void store8(__half* p, const float* o) {
    union { uint4 u; __half h[8]; } c;
#pragma unroll
    for (int j = 0; j < 8; ++j) c.h[j] = __float2half(o[j]);
    *(uint4*)p = c.u;
}

template <bool TANH, typename TOut>
__global__ __launch_bounds__(256) void k_gather_h(const int* __restrict__ off,
                                                  const int* __restrict__ eidx,
                                                  const __half* __restrict__ hs,
                                                  const float* __restrict__ dinv,
                                                  const float* __restrict__ bias,
                                                  TOut* __restrict__ out) {
    int tid = blockIdx.x * 256 + threadIdx.x;
    int r = tid >> 4;
    if (r >= N_NODES) return;
    int l = tid & 15;
    int f = l * 8;
    float acc[8];
    {
        union { uint4 u; __half2 h2[4]; } p;
        p.u = *(const uint4*)&hs[(size_t)r * 128 + f];
#pragma unroll
        for (int q = 0; q < 4; ++q) {
            float2 v = __half22float2(p.h2[q]);
            acc[2 * q] = 2.f * v.x;
            acc[2 * q + 1] = 2.f * v.y;
        }
    }
    int beg = off[r], end = off[r + 1];
    for (int i = beg; i < end; i += 16) {
        int n = end - i;
        if (n > 16) n = 16;
        int my = (l < n) ? eidx[i + l] : 0;
        for (int j = 0; j < n; ++j) {
            int s = __shfl(my, j, 16);
            union { uint4 u; __half2 h2[4]; } p;
            p.u = *(const uint4*)&hs[(size_t)s * 128 + f];
#pragma unroll
            for (int q = 0; q < 4; ++q) {
                float2 v = __half22float2(p.h2[q]);
                acc[2 * q] += v.x;
                acc[2 * q + 1] += v.y;
            }
        }
    }
    float dv = dinv[r];
    float o[8];
#pragma unroll
    for (int j = 0; j < 8; ++j) {
        float v = dv * acc[j] + bias[f + j];
        o[j] = TANH ? tanhf(v) : fmaxf(v, 0.f);
    }
    store8(out + (size_t)r * 128 + f, o);
}

// ====== fp32 gather for the last (F=16) layer ======
template <int LOGC, bool TANH>
__global__ __launch_bounds__(256) void k_gather(const int* __restrict__ off,
                                                const int* __restrict__ eidx,
                                                const float* __restrict__ hs,
                                                const float* __restrict__ dinv,
                                                const float* __restrict__ bias,
                                                float* __restrict__ out) {
    const int W = 1 << LOGC;
    const int F = 4 * W;
    int tid = blockIdx.x * 256 + threadIdx.x;
    int r = tid >> LOGC;
    if (r >= N_NODES) return;
    int l = tid & (W - 1);
    int f = l * 4;
    float4 h = *(const float4*)&hs[(size_t)r * F + f];
    float ax = 2.f * h.x, ay = 2.f * h.y, az = 2.f * h.z, aw = 2.f * h.w;
    int beg = off[r], end = off[r + 1];
    for (int i = beg; i < end; i += W) {
        int n = end - i;
        if (n > W) n = W;
        int my = (l < n) ? eidx[i + l] : 0;
        for (int j = 0; j < n; ++j) {
            int s = __shfl(my, j, W);
            float4 v = *(const float4*)&hs[(size_t)s * F + f];
            ax += v.x; ay += v.y; az += v.z; aw += v.w;
        }
    }
    float dv = dinv[r];
    float v0 = dv * ax + bias[f + 0];
    float v1 = dv * ay + bias[f + 1];
    float v2 = dv * az + bias[f + 2];
    float v3 = dv * aw + bias[f + 3];
    if (TANH) {
        v0 = tanhf(v0); v1 = tanhf(v1); v2 = tanhf(v2); v3 = tanhf(v3);
    } else {
        v0 = fmaxf(v0, 0.f); v1 = fmaxf(v1, 0.f);
        v2 = fmaxf(v2, 0.f); v3 = fmaxf(v3, 0.f);
    }
    *(float4*)&out[(size_t)r * F + f] = make_float4(v0, v1, v2, v3);
}

extern "C" void kernel_launch(void* const* d_in, const int* in_sizes, int n_in,
                              void* d_out, int out_size, void* d_ws, size_t ws_size,
                              hipStream_t stream) {
    const float* x  = (const float*)d_in[0];
    const int* ei   = (const int*)d_in[1];
    const float* W0 = (const float*)d_in[2];
    const float* b0 = (const float*)d_in[3];
    const float* W1 = (const float*)d_in[4];
    const float* b1 = (const float*)d_in[5];
    const float* W2 = (const float*)d_in[6];
    const float* b2 = (const float*)d_in[7];
    const float* W3 = (const float*)d_in[8];
    const float* b3 = (const float*)d_in[9];
    const int* src = ei;
    const int* dst = ei + N_EDGES;

    // ws layout (16B-aligned):
    __half* A    = (__half*)d_ws;                          // 50000*128 f16
    __half* Hh   = A + (size_t)N_NODES * 128;              // 50000*128 f16
    __half* WT   = Hh + (size_t)N_NODES * 128;             // 3 * 128*128 f16
    float*  H16  = (float*)(WT + 3 * 128 * 128);           // 50000*16 f32
    float*  dinv = H16 + (size_t)N_NODES * 16;             // 50000
    int* cnt    = (int*)(dinv + N_NODES);                  // 50000
    int* cur    = cnt + N_NODES;                           // 50000
    int* off    = cur + N_NODES;                           // 50016 (padded)
    int* eidx   = off + 50016;                             // 800000
    int* bsum   = eidx + N_EDGES;                          // 256
    int* boff   = bsum + 256;                              // 256

    // ---- CSR build + weight prep (every call; ws is re-poisoned) ----
    (void)hipMemsetAsync(cnt, 0, 2 * N_NODES * sizeof(int), stream);  // cnt+cur
    k_hist<<<(N_EDGES + 255) / 256, 256, 0, stream>>>(dst, cnt);
    k_scan_a<<<SCAN_BLOCKS, 256, 0, stream>>>(cnt, bsum);
    k_scan_b<<<1, 256, 0, stream>>>(bsum, boff, off);
    k_scan_c<<<SCAN_BLOCKS, 256, 0, stream>>>(cnt, boff, off, dinv);
    k_fill<<<(N_EDGES + 255) / 256, 256, 0, stream>>>(src, dst, off, cur, eidx);
    k_prepw<<<64, 256, 0, stream>>>(W0, WT);
    k_prepw<<<64, 256, 0, stream>>>(W1, WT + 128 * 128);
    k_prepw<<<64, 256, 0, stream>>>(W2, WT + 2 * 128 * 128);
    k_cast<<<N_NODES * 128 / 4 / 256, 256, 0, stream>>>(x, A);

    const int GB = (N_NODES + 63) / 64;  // mfma gemm blocks (64 rows each)
    // ---- layer 0 ----
    k_gemm_mfma<<<GB, 256, 0, stream>>>(A, WT, dinv, Hh);
    k_gather_h<false, __half><<<N_NODES * 16 / 256, 256, 0, stream>>>(
        off, eidx, Hh, dinv, b0, A);
    // ---- layer 1 ----
    k_gemm_mfma<<<GB, 256, 0, stream>>>(A, WT + 128 * 128, dinv, Hh);
    k_gather_h<false, __half><<<N_NODES * 16 / 256, 256, 0, stream>>>(
        off, eidx, Hh, dinv, b1, A);
    // ---- layer 2 ----
    k_gemm_mfma<<<GB, 256, 0, stream>>>(A, WT + 2 * 128 * 128, dinv, Hh);
    k_gather_h<false, __half><<<N_NODES * 16 / 256, 256, 0, stream>>>(
        off, eidx, Hh, dinv, b2, A);
    // ---- layer 3 (128 -> 16, tanh) ----
    k_gemm16<<<N_NODES * 16 / 256, 256, 0, stream>>>(A, W3, dinv, H16);
    k_gather<2, true><<<(N_NODES * 4 + 255) / 256, 256, 0, stream>>>(
        off, eidx, H16, dinv, b3, (float*)d_out);
}

// Round 8
// 359.445 us; speedup vs baseline: 12.5347x; 1.0333x over previous
//
#include <hip/hip_runtime.h>
#include <hip/hip_fp16.h>
#include <math.h>

#define N_NODES 50000
#define N_EDGES 800000
#define SCAN_BLOCKS 196   // ceil(50000/256)
#define NB 782            // ceil(50000/64) buckets of 64 nodes
#define CH 4096           // edges per k_bucket block
#define BUCKET_BLOCKS 196 // ceil(800000/4096)

typedef _Float16 half8 __attribute__((ext_vector_type(8)));
typedef float floatx4 __attribute__((ext_vector_type(4)));

// ================= CSR build (by dst) =================
__global__ __launch_bounds__(256) void k_hist(const int* __restrict__ dst,
                                              int* __restrict__ cnt) {
    int e = blockIdx.x * 256 + threadIdx.x;
    if (e < N_EDGES) atomicAdd(&cnt[dst[e]], 1);
}

__global__ __launch_bounds__(256) void k_scan_a(const int* __restrict__ cnt,
                                                int* __restrict__ bsum) {
    __shared__ int ls[256];
    int t = threadIdx.x;
    int i = blockIdx.x * 256 + t;
    ls[t] = (i < N_NODES) ? cnt[i] : 0;
    __syncthreads();
    for (int d = 128; d > 0; d >>= 1) {
        if (t < d) ls[t] += ls[t + d];
        __syncthreads();
    }
    if (t == 0) bsum[blockIdx.x] = ls[0];
}

__global__ __launch_bounds__(256) void k_scan_b(const int* __restrict__ bsum,
                                                int* __restrict__ boff,
                                                int* __restrict__ off) {
    __shared__ int ls[256];
    int t = threadIdx.x;
    int v = (t < SCAN_BLOCKS) ? bsum[t] : 0;
    ls[t] = v;
    __syncthreads();
    for (int d = 1; d < 256; d <<= 1) {
        int u = (t >= d) ? ls[t - d] : 0;
        __syncthreads();
        ls[t] += u;
        __syncthreads();
    }
    if (t < SCAN_BLOCKS) boff[t] = ls[t] - v;  // exclusive
    if (t == 0) off[N_NODES] = N_EDGES;
}

__global__ __launch_bounds__(256) void k_scan_c(const int* __restrict__ cnt,
                                                const int* __restrict__ boff,
                                                int* __restrict__ off,
                                                float* __restrict__ dinv) {
    __shared__ int ls[256];
    int t = threadIdx.x;
    int i = blockIdx.x * 256 + t;
    int v = (i < N_NODES) ? cnt[i] : 0;
    ls[t] = v;
    __syncthreads();
    for (int d = 1; d < 256; d <<= 1) {
        int u = (t >= d) ? ls[t - d] : 0;
        __syncthreads();
        ls[t] += u;
        __syncthreads();
    }
    if (i < N_NODES) {
        off[i] = boff[blockIdx.x] + ls[t] - v;  // exclusive
        dinv[i] = rsqrtf((float)v + 2.0f);      // improved: +2 self loop
    }
}

// ---- pass 1: LDS-staged bucket scatter. bucket = dst>>6. pack (dst<<16)|src.
__global__ __launch_bounds__(256) void k_bucket(const int* __restrict__ src,
                                                const int* __restrict__ dst,
                                                const int* __restrict__ off,
                                                int* __restrict__ gcur,
                                                unsigned* __restrict__ arena) {
    __shared__ int cntA[NB + 2];
    __shared__ int lofs[NB + 2];
    __shared__ int gbase[NB + 2];
    __shared__ int loff64[NB + 2];
    __shared__ int part[256];
    __shared__ unsigned buf[CH];
    const int t = threadIdx.x;
    const int ebase = blockIdx.x * CH;
    const int chunkN = min(CH, N_EDGES - ebase);

    // zero counters + stage off64
    for (int i = t; i < NB; i += 256) {
        cntA[i] = 0;
        loff64[i] = off[i << 6];
    }
    __syncthreads();
    // count buckets
    for (int i = t; i < chunkN; i += 256) {
        int b = dst[ebase + i] >> 6;
        atomicAdd(&cntA[b], 1);
    }
    __syncthreads();
    // exclusive scan of cntA -> lofs; reserve global sub-ranges; zero cntA
    int c[4];
    int s = 0;
#pragma unroll
    for (int q = 0; q < 4; ++q) {
        int idx = t * 4 + q;
        c[q] = (idx < NB) ? cntA[idx] : 0;
        s += c[q];
    }
    part[t] = s;
    __syncthreads();
    for (int d = 1; d < 256; d <<= 1) {
        int u = (t >= d) ? part[t - d] : 0;
        __syncthreads();
        part[t] += u;
        __syncthreads();
    }
    int run = (t > 0) ? part[t - 1] : 0;
#pragma unroll
    for (int q = 0; q < 4; ++q) {
        int idx = t * 4 + q;
        if (idx < NB) {
            lofs[idx] = run;
            run += c[q];
            gbase[idx] = (c[q] > 0) ? atomicAdd(&gcur[idx], c[q]) : 0;
            cntA[idx] = 0;  // reuse as placement cursor
        }
    }
    __syncthreads();
    // place packed edges into LDS ordered by bucket
    for (int i = t; i < chunkN; i += 256) {
        int d = dst[ebase + i];
        int sv = src[ebase + i];
        int b = d >> 6;
        int pos = atomicAdd(&cntA[b], 1);
        buf[lofs[b] + pos] = ((unsigned)d << 16) | (unsigned)sv;
    }
    __syncthreads();
    // flush: contiguous per-bucket bursts to the arena
    for (int i = t; i < chunkN; i += 256) {
        unsigned v = buf[i];
        int b = (int)(v >> 16) >> 6;
        int q = i - lofs[b];
        arena[loff64[b] + gbase[b] + q] = v;
    }
}

// ---- pass 2: per-bucket CSR finalize, LDS cursors, line-local writes ------
__global__ __launch_bounds__(256) void k_fill2(const int* __restrict__ off,
                                               const unsigned* __restrict__ arena,
                                               int* __restrict__ eidx) {
    __shared__ int cur64[64];
    const int t = threadIdx.x;
    const int nb = blockIdx.x * 64;
    if (t < 64) cur64[t] = off[min(nb + t, N_NODES)];
    __syncthreads();
    int ebeg = cur64[0];
    int eend = off[min(nb + 64, N_NODES)];
    for (int i = ebeg + t; i < eend; i += 256) {
        unsigned v = arena[i];
        int d = (int)(v >> 16);
        int slot = atomicAdd(&cur64[d - nb], 1);
        eidx[slot] = (int)(v & 0xFFFFu);
    }
}

// ---- x (fp32) -> fp16, vectorized ----
__global__ __launch_bounds__(256) void k_cast(const float* __restrict__ x,
                                              __half* __restrict__ xh) {
    int i = blockIdx.x * 256 + threadIdx.x;  // float4-granular; grid exact
    float4 v = *(const float4*)&x[(size_t)i * 4];
    union { ushort4 u; __half h[4]; } p;
    p.h[0] = __float2half(v.x); p.h[1] = __float2half(v.y);
    p.h[2] = __float2half(v.z); p.h[3] = __float2half(v.w);
    *(ushort4*)&xh[(size_t)i * 4] = p.u;
}

// ---- 3x W (fp32 [k][n] 128x128) -> fp16 W^T [n][k], single launch ---------
__global__ __launch_bounds__(256) void k_prepw(const float* __restrict__ Wa,
                                               const float* __restrict__ Wb,
                                               const float* __restrict__ Wc,
                                               __half* __restrict__ WT) {
    int which = blockIdx.x >> 6;  // 64 blocks per matrix
    const float* W = (which == 0) ? Wa : (which == 1) ? Wb : Wc;
    int i = (blockIdx.x & 63) * 256 + threadIdx.x;  // 16384 per matrix
    int k = i >> 7, n = i & 127;
    WT[which * 128 * 128 + n * 128 + k] = __float2half(W[i]);
}

// ====== MFMA GEMM: hs = fp16((Ah @ W) * dinv[row]) via W^T fp16 ============
__global__ __launch_bounds__(256) void k_gemm_mfma(const __half* __restrict__ Ah,
                                                   const __half* __restrict__ WT,
                                                   const float* __restrict__ dinv,
                                                   __half* __restrict__ hs) {
    const int tid = threadIdx.x;
    const int wave = tid >> 6;
    const int lane = tid & 63;
    const int m = lane & 15;
    const int quad = lane >> 4;
    const int rowA = blockIdx.x * 64 + wave * 16 + m;
    const int rA = (rowA < N_NODES) ? rowA : 0;
    const __half* arow = Ah + (size_t)rA * 128 + quad * 8;

    floatx4 acc[8] = {};
#pragma unroll
    for (int kb = 0; kb < 4; ++kb) {
        half8 af = *(const half8*)(arow + kb * 32);
#pragma unroll
        for (int nt = 0; nt < 8; ++nt) {
            half8 bf = *(const half8*)(WT + (size_t)(nt * 16 + m) * 128 +
                                       kb * 32 + quad * 8);
            acc[nt] = __builtin_amdgcn_mfma_f32_16x16x32_f16(af, bf, acc[nt],
                                                             0, 0, 0);
        }
    }
    // C/D: col = lane&15 (=m), row = quad*4 + reg
    const int rb = blockIdx.x * 64 + wave * 16 + quad * 4;
#pragma unroll
    for (int r = 0; r < 4; ++r) {
        int row = rb + r;
        if (row < N_NODES) {
            float dv = dinv[row];
            __half* orow = hs + (size_t)row * 128 + m;
#pragma unroll
            for (int nt = 0; nt < 8; ++nt)
                orow[nt * 16] = __float2half(acc[nt][r] * dv);
        }
    }
}

// ---- dense transform, F_out = 16 (last layer): fp16 in, fp32 out ----------
__global__ __launch_bounds__(256) void k_gemm16(const __half* __restrict__ in,
                                                const float* __restrict__ W,
                                                const float* __restrict__ dinv,
                                                float* __restrict__ hs) {
    __shared__ float Wt[16 * 132];
    const int tid = threadIdx.x;
    for (int i = tid; i < 128 * 16; i += 256) {
        int k = i >> 4, c = i & 15;
        Wt[c * 132 + k] = W[i];
    }
    __syncthreads();
    int gid = blockIdx.x * 256 + tid;  // grid exactly 50000*16
    int r = gid >> 4, c = gid & 15;
    const __half* arow = &in[(size_t)r * 128];
    const float* wrow = &Wt[c * 132];
    float acc = 0.f;
#pragma unroll
    for (int k0 = 0; k0 < 128; k0 += 8) {
        union { uint4 u; __half2 h2[4]; } p;
        p.u = *(const uint4*)&arow[k0];
#pragma unroll
        for (int q = 0; q < 4; ++q) {
            float2 a = __half22float2(p.h2[q]);
            acc += a.x * wrow[k0 + 2 * q] + a.y * wrow[k0 + 2 * q + 1];
        }
    }
    hs[gid] = acc * dinv[r];
}

// ====== fused aggregate + epilogue, fp16 H, F=128, templated output ========
__device__ __forceinline__ void store8(float* p, const float* o) {
    *(float4*)p = make_float4(o[0], o[1], o[2], o[3]);
    *(float4*)(p + 4) = make_float4(o[4], o[5], o[6], o[7]);
}
__device__ __forceinline__ void store8(__half* p, const float* o) {
    union { uint4 u; __half h[8]; } c;
#pragma unroll
    for (int j = 0; j < 8; ++j) c.h[j] = __float2half(o[j]);
    *(uint4*)p = c.u;
}

template <bool TANH, typename TOut>
__global__ __launch_bounds__(256) void k_gather_h(const int* __restrict__ off,
                                                  const int* __restrict__ eidx,
                                                  const __half* __restrict__ hs,
                                                  const float* __restrict__ dinv,
                                                  const float* __restrict__ bias,
                                                  TOut* __restrict__ out) {
    int tid = blockIdx.x * 256 + threadIdx.x;
    int r = tid >> 4;
    if (r >= N_NODES) return;
    int l = tid & 15;
    int f = l * 8;
    float acc[8];
    {
        union { uint4 u; __half2 h2[4]; } p;
        p.u = *(const uint4*)&hs[(size_t)r * 128 + f];
#pragma unroll
        for (int q = 0; q < 4; ++q) {
            float2 v = __half22float2(p.h2[q]);
            acc[2 * q] = 2.f * v.x;
            acc[2 * q + 1] = 2.f * v.y;
        }
    }
    int beg = off[r], end = off[r + 1];
    for (int i = beg; i < end; i += 16) {
        int n = end - i;
        if (n > 16) n = 16;
        int my = (l < n) ? eidx[i + l] : 0;
        for (int j = 0; j < n; ++j) {
            int s = __shfl(my, j, 16);
            union { uint4 u; __half2 h2[4]; } p;
            p.u = *(const uint4*)&hs[(size_t)s * 128 + f];
#pragma unroll
            for (int q = 0; q < 4; ++q) {
                float2 v = __half22float2(p.h2[q]);
                acc[2 * q] += v.x;
                acc[2 * q + 1] += v.y;
            }
        }
    }
    float dv = dinv[r];
    float o[8];
#pragma unroll
    for (int j = 0; j < 8; ++j) {
        float v = dv * acc[j] + bias[f + j];
        o[j] = TANH ? tanhf(v) : fmaxf(v, 0.f);
    }
    store8(out + (size_t)r * 128 + f, o);
}

// ====== fp32 gather for the last (F=16) layer ======
template <int LOGC, bool TANH>
__global__ __launch_bounds__(256) void k_gather(const int* __restrict__ off,
                                                const int* __restrict__ eidx,
                                                const float* __restrict__ hs,
                                                const float* __restrict__ dinv,
                                                const float* __restrict__ bias,
                                                float* __restrict__ out) {
    const int W = 1 << LOGC;
    const int F = 4 * W;
    int tid = blockIdx.x * 256 + threadIdx.x;
    int r = tid >> LOGC;
    if (r >= N_NODES) return;
    int l = tid & (W - 1);
    int f = l * 4;
    float4 h = *(const float4*)&hs[(size_t)r * F + f];
    float ax = 2.f * h.x, ay = 2.f * h.y, az = 2.f * h.z, aw = 2.f * h.w;
    int beg = off[r], end = off[r + 1];
    for (int i = beg; i < end; i += W) {
        int n = end - i;
        if (n > W) n = W;
        int my = (l < n) ? eidx[i + l] : 0;
        for (int j = 0; j < n; ++j) {
            int s = __shfl(my, j, W);
            float4 v = *(const float4*)&hs[(size_t)s * F + f];
            ax += v.x; ay += v.y; az += v.z; aw += v.w;
        }
    }
    float dv = dinv[r];
    float v0 = dv * ax + bias[f + 0];
    float v1 = dv * ay + bias[f + 1];
    float v2 = dv * az + bias[f + 2];
    float v3 = dv * aw + bias[f + 3];
    if (TANH) {
        v0 = tanhf(v0); v1 = tanhf(v1); v2 = tanhf(v2); v3 = tanhf(v3);
    } else {
        v0 = fmaxf(v0, 0.f); v1 = fmaxf(v1, 0.f);
        v2 = fmaxf(v2, 0.f); v3 = fmaxf(v3, 0.f);
    }
    *(float4*)&out[(size_t)r * F + f] = make_float4(v0, v1, v2, v3);
}

extern "C" void kernel_launch(void* const* d_in, const int* in_sizes, int n_in,
                              void* d_out, int out_size, void* d_ws, size_t ws_size,
                              hipStream_t stream) {
    const float* x  = (const float*)d_in[0];
    const int* ei   = (const int*)d_in[1];
    const float* W0 = (const float*)d_in[2];
    const float* b0 = (const float*)d_in[3];
    const float* W1 = (const float*)d_in[4];
    const float* b1 = (const float*)d_in[5];
    const float* W2 = (const float*)d_in[6];
    const float* b2 = (const float*)d_in[7];
    const float* W3 = (const float*)d_in[8];
    const float* b3 = (const float*)d_in[9];
    const int* src = ei;
    const int* dst = ei + N_EDGES;

    // ws layout (16B-aligned):
    __half* A    = (__half*)d_ws;                          // 50000*128 f16
    __half* Hh   = A + (size_t)N_NODES * 128;              // 50000*128 f16
    __half* WT   = Hh + (size_t)N_NODES * 128;             // 3 * 128*128 f16
    float*  H16  = (float*)(WT + 3 * 128 * 128);           // 50000*16 f32
    float*  dinv = H16 + (size_t)N_NODES * 16;             // 50000
    int* cnt    = (int*)(dinv + N_NODES);                  // 50000
    int* gcur   = cnt + N_NODES;                           // 1024 (NB padded)
    int* off    = gcur + 1024;                             // 50016 (padded)
    int* eidx   = off + 50016;                             // 800000
    int* bsum   = eidx + N_EDGES;                          // 256
    int* boff   = bsum + 256;                              // 256
    unsigned* arena = (unsigned*)(boff + 256);             // 800000

    // ---- CSR build + weight prep (every call; ws is re-poisoned) ----
    (void)hipMemsetAsync(cnt, 0, (N_NODES + 1024) * sizeof(int), stream);
    k_hist<<<(N_EDGES + 255) / 256, 256, 0, stream>>>(dst, cnt);
    k_scan_a<<<SCAN_BLOCKS, 256, 0, stream>>>(cnt, bsum);
    k_scan_b<<<1, 256, 0, stream>>>(bsum, boff, off);
    k_scan_c<<<SCAN_BLOCKS, 256, 0, stream>>>(cnt, boff, off, dinv);
    k_bucket<<<BUCKET_BLOCKS, 256, 0, stream>>>(src, dst, off, gcur, arena);
    k_fill2<<<NB, 256, 0, stream>>>(off, arena, eidx);
    k_prepw<<<192, 256, 0, stream>>>(W0, W1, W2, WT);
    k_cast<<<N_NODES * 128 / 4 / 256, 256, 0, stream>>>(x, A);

    const int GB = (N_NODES + 63) / 64;  // mfma gemm blocks (64 rows each)
    // ---- layer 0 ----
    k_gemm_mfma<<<GB, 256, 0, stream>>>(A, WT, dinv, Hh);
    k_gather_h<false, __half><<<N_NODES * 16 / 256, 256, 0, stream>>>(
        off, eidx, Hh, dinv, b0, A);
    // ---- layer 1 ----
    k_gemm_mfma<<<GB, 256, 0, stream>>>(A, WT + 128 * 128, dinv, Hh);
    k_gather_h<false, __half><<<N_NODES * 16 / 256, 256, 0, stream>>>(
        off, eidx, Hh, dinv, b1, A);
    // ---- layer 2 ----
    k_gemm_mfma<<<GB, 256, 0, stream>>>(A, WT + 2 * 128 * 128, dinv, Hh);
    k_gather_h<false, __half><<<N_NODES * 16 / 256, 256, 0, stream>>>(
        off, eidx, Hh, dinv, b2, A);
    // ---- layer 3 (128 -> 16, tanh) ----
    k_gemm16<<<N_NODES * 16 / 256, 256, 0, stream>>>(A, W3, dinv, H16);
    k_gather<2, true><<<(N_NODES * 4 + 255) / 256, 256, 0, stream>>>(
        off, eidx, H16, dinv, b3, (float*)d_out);
}

// Round 9
// 319.616 us; speedup vs baseline: 14.0967x; 1.1246x over previous
//
#include <hip/hip_runtime.h>
#include <hip/hip_fp16.h>
#include <math.h>

#define N_NODES 50000
#define N_EDGES 800000
#define NB 782            // ceil(50000/64) buckets of 64 dst nodes
#define CH 4096           // edges per k_bucket block
#define CAP 2048          // arena slots per bucket (Poisson(1024) -> 2x slack)
#define BUCKET_BLOCKS 196 // ceil(800000/4096)
#define CAST_BLOCKS 6250  // N_NODES*128/4/256
#define PREPW_BLOCKS 192  // 3 * 16384/256
#define FILL_GRID (NB + CAST_BLOCKS + PREPW_BLOCKS)

typedef _Float16 half8 __attribute__((ext_vector_type(8)));
typedef float floatx4 __attribute__((ext_vector_type(4)));

// ---- pass 1: LDS-staged bucket scatter into padded arena ------------------
// bucket = dst>>6, segment base = b*CAP, edge packed (dst<<16)|src.
__global__ __launch_bounds__(256) void k_bucket(const int* __restrict__ src,
                                                const int* __restrict__ dst,
                                                int* __restrict__ gcur,
                                                unsigned* __restrict__ arena) {
    __shared__ int cntA[NB];
    __shared__ int lofs[NB];
    __shared__ int gbase[NB];
    __shared__ int part[256];
    __shared__ unsigned buf[CH];
    const int t = threadIdx.x;
    const int ebase = blockIdx.x * CH;
    const int chunkN = min(CH, N_EDGES - ebase);

    for (int i = t; i < NB; i += 256) cntA[i] = 0;
    __syncthreads();
    for (int i = t; i < chunkN; i += 256)
        atomicAdd(&cntA[dst[ebase + i] >> 6], 1);
    __syncthreads();
    // exclusive scan of cntA -> lofs; reserve arena sub-ranges via gcur
    int c[4];
    int s = 0;
#pragma unroll
    for (int q = 0; q < 4; ++q) {
        int idx = t * 4 + q;
        c[q] = (idx < NB) ? cntA[idx] : 0;
        s += c[q];
    }
    part[t] = s;
    __syncthreads();
    for (int d = 1; d < 256; d <<= 1) {
        int u = (t >= d) ? part[t - d] : 0;
        __syncthreads();
        part[t] += u;
        __syncthreads();
    }
    int run = (t > 0) ? part[t - 1] : 0;
#pragma unroll
    for (int q = 0; q < 4; ++q) {
        int idx = t * 4 + q;
        if (idx < NB) {
            lofs[idx] = run;
            run += c[q];
            gbase[idx] = (c[q] > 0) ? atomicAdd(&gcur[idx], c[q]) : 0;
            cntA[idx] = 0;  // reuse as placement cursor
        }
    }
    __syncthreads();
    // place packed edges into LDS ordered by bucket
    for (int i = t; i < chunkN; i += 256) {
        int d = dst[ebase + i];
        int sv = src[ebase + i];
        int b = d >> 6;
        int pos = atomicAdd(&cntA[b], 1);
        buf[lofs[b] + pos] = ((unsigned)d << 16) | (unsigned)sv;
    }
    __syncthreads();
    // flush contiguous per-bucket bursts into the padded arena
    for (int i = t; i < chunkN; i += 256) {
        unsigned v = buf[i];
        int b = (int)(v >> 16) >> 6;
        int q = i - lofs[b];
        int p = gbase[b] + q;
        if (p < CAP) arena[((size_t)b << 11) + p] = v;
    }
}

// ---- pass 2 (fused): bucket finalize | x->fp16 cast | W->fp16 W^T ---------
// finalize: per-bucket local counts -> wave scan -> packed off|deg, dinv,
// sorted eidx (writes land in one 8KB region per block).
__global__ __launch_bounds__(256) void k_fill3prep(
    const unsigned* __restrict__ arena, const int* __restrict__ gcur,
    unsigned* __restrict__ packed, float* __restrict__ dinv,
    int* __restrict__ eidx, const float* __restrict__ x,
    __half* __restrict__ xh, const float* __restrict__ W0,
    const float* __restrict__ W1, const float* __restrict__ W2,
    __half* __restrict__ WT) {
    const int t = threadIdx.x;
    if (blockIdx.x < NB) {
        const int b = blockIdx.x;
        __shared__ int cnt64[64];
        __shared__ int cur64[64];
        if (t < 64) cnt64[t] = 0;
        __syncthreads();
        const int seglen = min(gcur[b], CAP);
        const unsigned* seg = arena + ((size_t)b << 11);
        for (int i = t; i < seglen; i += 256)
            atomicAdd(&cnt64[(seg[i] >> 16) & 63], 1);
        __syncthreads();
        if (t < 64) {  // one wave: prefix scan of 64 counts
            int v = cnt64[t];
            int p = v;
#pragma unroll
            for (int d = 1; d < 64; d <<= 1) {
                int u = __shfl_up(p, d, 64);
                if (t >= d) p += u;
            }
            int excl = p - v;
            int node = b * 64 + t;
            if (node < N_NODES) {
                packed[node] =
                    ((unsigned)((b << 11) + excl) << 11) | (unsigned)v;
                dinv[node] = rsqrtf((float)v + 2.0f);  // improved: +2
            }
            cur64[t] = excl;
        }
        __syncthreads();
        const int base = b << 11;
        for (int i = t; i < seglen; i += 256) {
            unsigned v = seg[i];
            int d = (int)(v >> 16) & 63;
            int pos = atomicAdd(&cur64[d], 1);
            eidx[base + pos] = (int)(v & 0xFFFFu);
        }
    } else if (blockIdx.x < NB + CAST_BLOCKS) {
        int i = (blockIdx.x - NB) * 256 + t;  // float4-granular, exact
        float4 v = *(const float4*)&x[(size_t)i * 4];
        union { ushort4 u; __half h[4]; } p;
        p.h[0] = __float2half(v.x); p.h[1] = __float2half(v.y);
        p.h[2] = __float2half(v.z); p.h[3] = __float2half(v.w);
        *(ushort4*)&xh[(size_t)i * 4] = p.u;
    } else {
        int idx = blockIdx.x - NB - CAST_BLOCKS;  // 0..191
        int which = idx >> 6;
        const float* W = (which == 0) ? W0 : (which == 1) ? W1 : W2;
        int i = (idx & 63) * 256 + t;  // 16384 per matrix
        int k = i >> 7, n = i & 127;
        WT[which * 128 * 128 + n * 128 + k] = __float2half(W[i]);
    }
}

// ====== MFMA GEMM: hs = fp16((Ah @ W) * dinv[row]) via W^T fp16 ============
__global__ __launch_bounds__(256) void k_gemm_mfma(const __half* __restrict__ Ah,
                                                   const __half* __restrict__ WT,
                                                   const float* __restrict__ dinv,
                                                   __half* __restrict__ hs) {
    const int tid = threadIdx.x;
    const int wave = tid >> 6;
    const int lane = tid & 63;
    const int m = lane & 15;
    const int quad = lane >> 4;
    const int rowA = blockIdx.x * 64 + wave * 16 + m;
    const int rA = (rowA < N_NODES) ? rowA : 0;
    const __half* arow = Ah + (size_t)rA * 128 + quad * 8;

    floatx4 acc[8] = {};
#pragma unroll
    for (int kb = 0; kb < 4; ++kb) {
        half8 af = *(const half8*)(arow + kb * 32);
#pragma unroll
        for (int nt = 0; nt < 8; ++nt) {
            half8 bf = *(const half8*)(WT + (size_t)(nt * 16 + m) * 128 +
                                       kb * 32 + quad * 8);
            acc[nt] = __builtin_amdgcn_mfma_f32_16x16x32_f16(af, bf, acc[nt],
                                                             0, 0, 0);
        }
    }
    // C/D: col = lane&15 (=m), row = quad*4 + reg
    const int rb = blockIdx.x * 64 + wave * 16 + quad * 4;
#pragma unroll
    for (int r = 0; r < 4; ++r) {
        int row = rb + r;
        if (row < N_NODES) {
            float dv = dinv[row];
            __half* orow = hs + (size_t)row * 128 + m;
#pragma unroll
            for (int nt = 0; nt < 8; ++nt)
                orow[nt * 16] = __float2half(acc[nt][r] * dv);
        }
    }
}

// ---- dense transform, F_out = 16 (last layer): fp16 in, fp32 out ----------
__global__ __launch_bounds__(256) void k_gemm16(const __half* __restrict__ in,
                                                const float* __restrict__ W,
                                                const float* __restrict__ dinv,
                                                float* __restrict__ hs) {
    __shared__ float Wt[16 * 132];
    const int tid = threadIdx.x;
    for (int i = tid; i < 128 * 16; i += 256) {
        int k = i >> 4, c = i & 15;
        Wt[c * 132 + k] = W[i];
    }
    __syncthreads();
    int gid = blockIdx.x * 256 + tid;  // grid exactly 50000*16
    int r = gid >> 4, c = gid & 15;
    const __half* arow = &in[(size_t)r * 128];
    const float* wrow = &Wt[c * 132];
    float acc = 0.f;
#pragma unroll
    for (int k0 = 0; k0 < 128; k0 += 8) {
        union { uint4 u; __half2 h2[4]; } p;
        p.u = *(const uint4*)&arow[k0];
#pragma unroll
        for (int q = 0; q < 4; ++q) {
            float2 a = __half22float2(p.h2[q]);
            acc += a.x * wrow[k0 + 2 * q] + a.y * wrow[k0 + 2 * q + 1];
        }
    }
    hs[gid] = acc * dinv[r];
}

// ====== fused aggregate + epilogue, fp16 H, F=128 ======
__device__ __forceinline__ void acc8(const __half* p, float* acc) {
    union { uint4 u; __half2 h2[4]; } t;
    t.u = *(const uint4*)p;
#pragma unroll
    for (int q = 0; q < 4; ++q) {
        float2 v = __half22float2(t.h2[q]);
        acc[2 * q] += v.x;
        acc[2 * q + 1] += v.y;
    }
}
__device__ __forceinline__ void store8(float* p, const float* o) {
    *(float4*)p = make_float4(o[0], o[1], o[2], o[3]);
    *(float4*)(p + 4) = make_float4(o[4], o[5], o[6], o[7]);
}
__device__ __forceinline__ void store8(__half* p, const float* o) {
    union { uint4 u; __half h[8]; } c;
#pragma unroll
    for (int j = 0; j < 8; ++j) c.h[j] = __float2half(o[j]);
    *(uint4*)p = c.u;
}

template <bool TANH, typename TOut>
__global__ __launch_bounds__(256) void k_gather_h(const unsigned* __restrict__ packed,
                                                  const int* __restrict__ eidx,
                                                  const __half* __restrict__ hs,
                                                  const float* __restrict__ dinv,
                                                  const float* __restrict__ bias,
                                                  TOut* __restrict__ out) {
    int tid = blockIdx.x * 256 + threadIdx.x;
    int r = tid >> 4;
    if (r >= N_NODES) return;
    int l = tid & 15;
    int f = l * 8;
    float acc[8];
    {
        union { uint4 u; __half2 h2[4]; } p;
        p.u = *(const uint4*)&hs[(size_t)r * 128 + f];
#pragma unroll
        for (int q = 0; q < 4; ++q) {
            float2 v = __half22float2(p.h2[q]);
            acc[2 * q] = 2.f * v.x;
            acc[2 * q + 1] = 2.f * v.y;
        }
    }
    unsigned pk = packed[r];
    int i = (int)(pk >> 11);
    int end = i + (int)(pk & 2047u);
    // full 16-edge batches, fully unrolled (16 loads in flight)
    for (; i + 16 <= end; i += 16) {
        int my = eidx[i + l];
#pragma unroll
        for (int j = 0; j < 16; ++j) {
            int s = __shfl(my, j, 16);
            acc8(&hs[(size_t)s * 128 + f], acc);
        }
    }
    if (i < end) {
        int n = end - i;
        int my = (l < n) ? eidx[i + l] : 0;
        for (int j = 0; j < n; ++j) {
            int s = __shfl(my, j, 16);
            acc8(&hs[(size_t)s * 128 + f], acc);
        }
    }
    float dv = dinv[r];
    float o[8];
#pragma unroll
    for (int j = 0; j < 8; ++j) {
        float v = dv * acc[j] + bias[f + j];
        o[j] = TANH ? tanhf(v) : fmaxf(v, 0.f);
    }
    store8(out + (size_t)r * 128 + f, o);
}

// ====== fp32 gather for the last (F=16) layer ======
template <bool TANH>
__global__ __launch_bounds__(256) void k_gather4(const unsigned* __restrict__ packed,
                                                 const int* __restrict__ eidx,
                                                 const float* __restrict__ hs,
                                                 const float* __restrict__ dinv,
                                                 const float* __restrict__ bias,
                                                 float* __restrict__ out) {
    int tid = blockIdx.x * 256 + threadIdx.x;
    int r = tid >> 2;
    if (r >= N_NODES) return;
    int l = tid & 3;
    int f = l * 4;
    float4 h = *(const float4*)&hs[(size_t)r * 16 + f];
    float ax = 2.f * h.x, ay = 2.f * h.y, az = 2.f * h.z, aw = 2.f * h.w;
    unsigned pk = packed[r];
    int i = (int)(pk >> 11);
    int end = i + (int)(pk & 2047u);
    for (; i + 4 <= end; i += 4) {
        int my = eidx[i + l];
#pragma unroll
        for (int j = 0; j < 4; ++j) {
            int s = __shfl(my, j, 4);
            float4 v = *(const float4*)&hs[(size_t)s * 16 + f];
            ax += v.x; ay += v.y; az += v.z; aw += v.w;
        }
    }
    if (i < end) {
        int n = end - i;
        int my = (l < n) ? eidx[i + l] : 0;
        for (int j = 0; j < n; ++j) {
            int s = __shfl(my, j, 4);
            float4 v = *(const float4*)&hs[(size_t)s * 16 + f];
            ax += v.x; ay += v.y; az += v.z; aw += v.w;
        }
    }
    float dv = dinv[r];
    float v0 = dv * ax + bias[f + 0];
    float v1 = dv * ay + bias[f + 1];
    float v2 = dv * az + bias[f + 2];
    float v3 = dv * aw + bias[f + 3];
    if (TANH) {
        v0 = tanhf(v0); v1 = tanhf(v1); v2 = tanhf(v2); v3 = tanhf(v3);
    } else {
        v0 = fmaxf(v0, 0.f); v1 = fmaxf(v1, 0.f);
        v2 = fmaxf(v2, 0.f); v3 = fmaxf(v3, 0.f);
    }
    *(float4*)&out[(size_t)r * 16 + f] = make_float4(v0, v1, v2, v3);
}

extern "C" void kernel_launch(void* const* d_in, const int* in_sizes, int n_in,
                              void* d_out, int out_size, void* d_ws, size_t ws_size,
                              hipStream_t stream) {
    const float* x  = (const float*)d_in[0];
    const int* ei   = (const int*)d_in[1];
    const float* W0 = (const float*)d_in[2];
    const float* b0 = (const float*)d_in[3];
    const float* W1 = (const float*)d_in[4];
    const float* b1 = (const float*)d_in[5];
    const float* W2 = (const float*)d_in[6];
    const float* b2 = (const float*)d_in[7];
    const float* W3 = (const float*)d_in[8];
    const float* b3 = (const float*)d_in[9];
    const int* src = ei;
    const int* dst = ei + N_EDGES;

    // ws layout (16B-aligned):
    __half* A      = (__half*)d_ws;                        // 50000*128 f16
    __half* Hh     = A + (size_t)N_NODES * 128;            // 50000*128 f16
    __half* WT     = Hh + (size_t)N_NODES * 128;           // 3*128*128 f16
    float*  H16    = (float*)(WT + 3 * 128 * 128);         // 50000*16 f32
    float*  dinv   = H16 + (size_t)N_NODES * 16;           // 50000
    unsigned* packed = (unsigned*)(dinv + N_NODES);        // 50000
    int*    gcur   = (int*)(packed + N_NODES);             // 1024 (NB padded)
    int*    eidx   = gcur + 1024;                          // NB*CAP
    unsigned* arena = (unsigned*)(eidx + NB * CAP);        // NB*CAP

    // ---- CSR build + prep (every call; ws is re-poisoned) ----
    (void)hipMemsetAsync(gcur, 0, 1024 * sizeof(int), stream);
    k_bucket<<<BUCKET_BLOCKS, 256, 0, stream>>>(src, dst, gcur, arena);
    k_fill3prep<<<FILL_GRID, 256, 0, stream>>>(arena, gcur, packed, dinv,
                                               eidx, x, A, W0, W1, W2, WT);

    const int GB = (N_NODES + 63) / 64;  // mfma gemm blocks (64 rows each)
    // ---- layer 0 ----
    k_gemm_mfma<<<GB, 256, 0, stream>>>(A, WT, dinv, Hh);
    k_gather_h<false, __half><<<N_NODES * 16 / 256, 256, 0, stream>>>(
        packed, eidx, Hh, dinv, b0, A);
    // ---- layer 1 ----
    k_gemm_mfma<<<GB, 256, 0, stream>>>(A, WT + 128 * 128, dinv, Hh);
    k_gather_h<false, __half><<<N_NODES * 16 / 256, 256, 0, stream>>>(
        packed, eidx, Hh, dinv, b1, A);
    // ---- layer 2 ----
    k_gemm_mfma<<<GB, 256, 0, stream>>>(A, WT + 2 * 128 * 128, dinv, Hh);
    k_gather_h<false, __half><<<N_NODES * 16 / 256, 256, 0, stream>>>(
        packed, eidx, Hh, dinv, b2, A);
    // ---- layer 3 (128 -> 16, tanh) ----
    k_gemm16<<<N_NODES * 16 / 256, 256, 0, stream>>>(A, W3, dinv, H16);
    k_gather4<true><<<(N_NODES * 4 + 255) / 256, 256, 0, stream>>>(
        packed, eidx, H16, dinv, b3, (float*)d_out);
}

// Round 11
// 317.875 us; speedup vs baseline: 14.1739x; 1.0055x over previous
//
#include <hip/hip_runtime.h>
#include <hip/hip_fp16.h>
#include <math.h>

#define N_NODES 50000
#define N_EDGES 800000
#define NB 782            // ceil(50000/64) buckets of 64 dst nodes
#define CH 4096           // edges per k_bucket block
#define CAP 2048          // arena slots per bucket (Poisson(1024) -> 2x slack)
#define BUCKET_BLOCKS 196 // ceil(800000/4096)
#define CAST_BLOCKS 6250  // N_NODES*128/4/256
#define PREPW_BLOCKS 192  // 3 * 16384/256
#define FILL_GRID (NB + CAST_BLOCKS + PREPW_BLOCKS)

typedef _Float16 half8 __attribute__((ext_vector_type(8)));
typedef float floatx4 __attribute__((ext_vector_type(4)));
typedef unsigned uintx4 __attribute__((ext_vector_type(4)));

// ---- pass 1: LDS-staged bucket scatter into padded arena ------------------
// bucket = dst>>6, segment base = b*CAP, edge packed (dst<<16)|src.
__global__ __launch_bounds__(256) void k_bucket(const int* __restrict__ src,
                                                const int* __restrict__ dst,
                                                int* __restrict__ gcur,
                                                unsigned* __restrict__ arena) {
    __shared__ int cntA[NB];
    __shared__ int lofs[NB];
    __shared__ int gbase[NB];
    __shared__ int part[256];
    __shared__ unsigned buf[CH];
    const int t = threadIdx.x;
    const int ebase = blockIdx.x * CH;
    const int chunkN = min(CH, N_EDGES - ebase);

    for (int i = t; i < NB; i += 256) cntA[i] = 0;
    __syncthreads();
    for (int i = t; i < chunkN; i += 256)
        atomicAdd(&cntA[dst[ebase + i] >> 6], 1);
    __syncthreads();
    // exclusive scan of cntA -> lofs; reserve arena sub-ranges via gcur
    int c[4];
    int s = 0;
#pragma unroll
    for (int q = 0; q < 4; ++q) {
        int idx = t * 4 + q;
        c[q] = (idx < NB) ? cntA[idx] : 0;
        s += c[q];
    }
    part[t] = s;
    __syncthreads();
    for (int d = 1; d < 256; d <<= 1) {
        int u = (t >= d) ? part[t - d] : 0;
        __syncthreads();
        part[t] += u;
        __syncthreads();
    }
    int run = (t > 0) ? part[t - 1] : 0;
#pragma unroll
    for (int q = 0; q < 4; ++q) {
        int idx = t * 4 + q;
        if (idx < NB) {
            lofs[idx] = run;
            run += c[q];
            gbase[idx] = (c[q] > 0) ? atomicAdd(&gcur[idx], c[q]) : 0;
            cntA[idx] = 0;  // reuse as placement cursor
        }
    }
    __syncthreads();
    // place packed edges into LDS ordered by bucket
    for (int i = t; i < chunkN; i += 256) {
        int d = dst[ebase + i];
        int sv = src[ebase + i];
        int b = d >> 6;
        int pos = atomicAdd(&cntA[b], 1);
        buf[lofs[b] + pos] = ((unsigned)d << 16) | (unsigned)sv;
    }
    __syncthreads();
    // flush contiguous per-bucket bursts into the padded arena
    for (int i = t; i < chunkN; i += 256) {
        unsigned v = buf[i];
        int b = (int)(v >> 16) >> 6;
        int q = i - lofs[b];
        int p = gbase[b] + q;
        if (p < CAP) arena[((size_t)b << 11) + p] = v;
    }
}

// ---- pass 2 (fused): bucket finalize | x->fp16 cast | W->fp16 W^T ---------
// W^T is stored FEATURE-PERMUTED for the mfma epilogue: position n'=nt*16+m
// holds logical column m*8+nt, so each lane's 8 outputs are contiguous.
__global__ __launch_bounds__(256) void k_fill3prep(
    const unsigned* __restrict__ arena, const int* __restrict__ gcur,
    unsigned* __restrict__ packed, float* __restrict__ dinv,
    int* __restrict__ eidx, const float* __restrict__ x,
    __half* __restrict__ xh, const float* __restrict__ W0,
    const float* __restrict__ W1, const float* __restrict__ W2,
    __half* __restrict__ WT) {
    const int t = threadIdx.x;
    if (blockIdx.x < NB) {
        const int b = blockIdx.x;
        __shared__ int cnt64[64];
        __shared__ int cur64[64];
        if (t < 64) cnt64[t] = 0;
        __syncthreads();
        const int seglen = min(gcur[b], CAP);
        const unsigned* seg = arena + ((size_t)b << 11);
        for (int i = t; i < seglen; i += 256)
            atomicAdd(&cnt64[(seg[i] >> 16) & 63], 1);
        __syncthreads();
        if (t < 64) {  // one wave: prefix scan of 64 counts
            int v = cnt64[t];
            int p = v;
#pragma unroll
            for (int d = 1; d < 64; d <<= 1) {
                int u = __shfl_up(p, d, 64);
                if (t >= d) p += u;
            }
            int excl = p - v;
            int node = b * 64 + t;
            if (node < N_NODES) {
                packed[node] =
                    ((unsigned)((b << 11) + excl) << 11) | (unsigned)v;
                dinv[node] = rsqrtf((float)v + 2.0f);  // improved: +2
            }
            cur64[t] = excl;
        }
        __syncthreads();
        const int base = b << 11;
        for (int i = t; i < seglen; i += 256) {
            unsigned v = seg[i];
            int d = (int)(v >> 16) & 63;
            int pos = atomicAdd(&cur64[d], 1);
            eidx[base + pos] = (int)(v & 0xFFFFu);
        }
    } else if (blockIdx.x < NB + CAST_BLOCKS) {
        int i = (blockIdx.x - NB) * 256 + t;  // float4-granular, exact
        float4 v = *(const float4*)&x[(size_t)i * 4];
        union { ushort4 u; __half h[4]; } p;
        p.h[0] = __float2half(v.x); p.h[1] = __float2half(v.y);
        p.h[2] = __float2half(v.z); p.h[3] = __float2half(v.w);
        *(ushort4*)&xh[(size_t)i * 4] = p.u;
    } else {
        int idx = blockIdx.x - NB - CAST_BLOCKS;  // 0..191
        int which = idx >> 6;
        const float* W = (which == 0) ? W0 : (which == 1) ? W1 : W2;
        int i = (idx & 63) * 256 + t;  // 16384 per matrix: i = k*128 + n
        int k = i >> 7, n = i & 127;
        int np = ((n & 7) << 4) + (n >> 3);  // inverse of perm(n')=(n'&15)*8+(n'>>4)
        WT[which * 128 * 128 + np * 128 + k] = __float2half(W[i]);
    }
}

// ====== MFMA GEMM: hs = fp16((Ah @ W) * dinv[row]) via permuted W^T ========
// Lane (m,quad), call nt computes cols m*8+nt -> uintx4 row-segment stores.
__global__ __launch_bounds__(256) void k_gemm_mfma(const __half* __restrict__ Ah,
                                                   const __half* __restrict__ WT,
                                                   const float* __restrict__ dinv,
                                                   __half* __restrict__ hs) {
    const int tid = threadIdx.x;
    const int wave = tid >> 6;
    const int lane = tid & 63;
    const int m = lane & 15;
    const int quad = lane >> 4;
    const int rowA = blockIdx.x * 64 + wave * 16 + m;
    const int rA = (rowA < N_NODES) ? rowA : 0;
    const __half* arow = Ah + (size_t)rA * 128 + quad * 8;

    floatx4 acc[8] = {};
#pragma unroll
    for (int kb = 0; kb < 4; ++kb) {
        half8 af = __builtin_nontemporal_load((const half8*)(arow + kb * 32));
#pragma unroll
        for (int nt = 0; nt < 8; ++nt) {
            half8 bf = *(const half8*)(WT + (size_t)(nt * 16 + m) * 128 +
                                       kb * 32 + quad * 8);
            acc[nt] = __builtin_amdgcn_mfma_f32_16x16x32_f16(af, bf, acc[nt],
                                                             0, 0, 0);
        }
    }
    // C/D: physical col of (lane m, call nt) = m*8+nt; row = quad*4 + reg
    const int rb = blockIdx.x * 64 + wave * 16 + quad * 4;
#pragma unroll
    for (int r = 0; r < 4; ++r) {
        int row = rb + r;
        if (row < N_NODES) {
            float dv = dinv[row];
            union { uintx4 u; __half h[8]; } pk;
#pragma unroll
            for (int nt = 0; nt < 8; ++nt)
                pk.h[nt] = __float2half(acc[nt][r] * dv);
            *(uintx4*)(hs + (size_t)row * 128 + m * 8) = pk.u;
        }
    }
}

// ---- dense transform, F_out = 16 (last layer): fp16 in, fp32 out ----------
__global__ __launch_bounds__(256) void k_gemm16(const __half* __restrict__ in,
                                                const float* __restrict__ W,
                                                const float* __restrict__ dinv,
                                                float* __restrict__ hs) {
    __shared__ float Wt[16 * 132];
    const int tid = threadIdx.x;
    for (int i = tid; i < 128 * 16; i += 256) {
        int k = i >> 4, c = i & 15;
        Wt[c * 132 + k] = W[i];
    }
    __syncthreads();
    int gid = blockIdx.x * 256 + tid;  // grid exactly 50000*16
    int r = gid >> 4, c = gid & 15;
    const __half* arow = &in[(size_t)r * 128];
    const float* wrow = &Wt[c * 132];
    float acc = 0.f;
#pragma unroll
    for (int k0 = 0; k0 < 128; k0 += 8) {
        union { uint4 u; __half2 h2[4]; } p;
        p.u = *(const uint4*)&arow[k0];
#pragma unroll
        for (int q = 0; q < 4; ++q) {
            float2 a = __half22float2(p.h2[q]);
            acc += a.x * wrow[k0 + 2 * q] + a.y * wrow[k0 + 2 * q + 1];
        }
    }
    hs[gid] = acc * dinv[r];
}

// ====== fused aggregate + epilogue, fp16 H, F=128 ======
__device__ __forceinline__ void acc8(const __half* p, float* acc) {
    union { uint4 u; __half2 h2[4]; } t;
    t.u = *(const uint4*)p;
#pragma unroll
    for (int q = 0; q < 4; ++q) {
        float2 v = __half22float2(t.h2[q]);
        acc[2 * q] += v.x;
        acc[2 * q + 1] += v.y;
    }
}
// non-temporal output stores: don't evict the H table from L2
__device__ __forceinline__ void store8_nt(float* p, const float* o) {
    floatx4 a = {o[0], o[1], o[2], o[3]};
    floatx4 b = {o[4], o[5], o[6], o[7]};
    __builtin_nontemporal_store(a, (floatx4*)p);
    __builtin_nontemporal_store(b, (floatx4*)(p + 4));
}
__device__ __forceinline__ void store8_nt(__half* p, const float* o) {
    union { uintx4 u; __half h[8]; } c;
#pragma unroll
    for (int j = 0; j < 8; ++j) c.h[j] = __float2half(o[j]);
    __builtin_nontemporal_store(c.u, (uintx4*)p);
}

template <bool TANH, typename TOut>
__global__ __launch_bounds__(256) void k_gather_h(const unsigned* __restrict__ packed,
                                                  const int* __restrict__ eidx,
                                                  const __half* __restrict__ hs,
                                                  const float* __restrict__ dinv,
                                                  const float* __restrict__ bias,
                                                  TOut* __restrict__ out) {
    int tid = blockIdx.x * 256 + threadIdx.x;
    int r = tid >> 4;
    if (r >= N_NODES) return;
    int l = tid & 15;
    int f = l * 8;
    float acc[8];
    {
        union { uint4 u; __half2 h2[4]; } p;
        p.u = *(const uint4*)&hs[(size_t)r * 128 + f];
#pragma unroll
        for (int q = 0; q < 4; ++q) {
            float2 v = __half22float2(p.h2[q]);
            acc[2 * q] = 2.f * v.x;
            acc[2 * q + 1] = 2.f * v.y;
        }
    }
    unsigned pk = packed[r];
    int i = (int)(pk >> 11);
    int end = i + (int)(pk & 2047u);
    // full 16-edge batches, fully unrolled (16 loads in flight)
    for (; i + 16 <= end; i += 16) {
        int my = __builtin_nontemporal_load(&eidx[i + l]);
#pragma unroll
        for (int j = 0; j < 16; ++j) {
            int s = __shfl(my, j, 16);
            acc8(&hs[(size_t)s * 128 + f], acc);
        }
    }
    if (i < end) {
        int n = end - i;
        int my = (l < n) ? eidx[i + l] : 0;
        for (int j = 0; j < n; ++j) {
            int s = __shfl(my, j, 16);
            acc8(&hs[(size_t)s * 128 + f], acc);
        }
    }
    float dv = dinv[r];
    float o[8];
#pragma unroll
    for (int j = 0; j < 8; ++j) {
        float v = dv * acc[j] + bias[f + j];
        o[j] = TANH ? tanhf(v) : fmaxf(v, 0.f);
    }
    store8_nt(out + (size_t)r * 128 + f, o);
}

// ====== fp32 gather for the last (F=16) layer ======
template <bool TANH>
__global__ __launch_bounds__(256) void k_gather4(const unsigned* __restrict__ packed,
                                                 const int* __restrict__ eidx,
                                                 const float* __restrict__ hs,
                                                 const float* __restrict__ dinv,
                                                 const float* __restrict__ bias,
                                                 float* __restrict__ out) {
    int tid = blockIdx.x * 256 + threadIdx.x;
    int r = tid >> 2;
    if (r >= N_NODES) return;
    int l = tid & 3;
    int f = l * 4;
    float4 h = *(const float4*)&hs[(size_t)r * 16 + f];
    float ax = 2.f * h.x, ay = 2.f * h.y, az = 2.f * h.z, aw = 2.f * h.w;
    unsigned pk = packed[r];
    int i = (int)(pk >> 11);
    int end = i + (int)(pk & 2047u);
    for (; i + 4 <= end; i += 4) {
        int my = eidx[i + l];
#pragma unroll
        for (int j = 0; j < 4; ++j) {
            int s = __shfl(my, j, 4);
            float4 v = *(const float4*)&hs[(size_t)s * 16 + f];
            ax += v.x; ay += v.y; az += v.z; aw += v.w;
        }
    }
    if (i < end) {
        int n = end - i;
        int my = (l < n) ? eidx[i + l] : 0;
        for (int j = 0; j < n; ++j) {
            int s = __shfl(my, j, 4);
            float4 v = *(const float4*)&hs[(size_t)s * 16 + f];
            ax += v.x; ay += v.y; az += v.z; aw += v.w;
        }
    }
    float dv = dinv[r];
    float v0 = dv * ax + bias[f + 0];
    float v1 = dv * ay + bias[f + 1];
    float v2 = dv * az + bias[f + 2];
    float v3 = dv * aw + bias[f + 3];
    if (TANH) {
        v0 = tanhf(v0); v1 = tanhf(v1); v2 = tanhf(v2); v3 = tanhf(v3);
    } else {
        v0 = fmaxf(v0, 0.f); v1 = fmaxf(v1, 0.f);
        v2 = fmaxf(v2, 0.f); v3 = fmaxf(v3, 0.f);
    }
    floatx4 o = {v0, v1, v2, v3};
    __builtin_nontemporal_store(o, (floatx4*)&out[(size_t)r * 16 + f]);
}

extern "C" void kernel_launch(void* const* d_in, const int* in_sizes, int n_in,
                              void* d_out, int out_size, void* d_ws, size_t ws_size,
                              hipStream_t stream) {
    const float* x  = (const float*)d_in[0];
    const int* ei   = (const int*)d_in[1];
    const float* W0 = (const float*)d_in[2];
    const float* b0 = (const float*)d_in[3];
    const float* W1 = (const float*)d_in[4];
    const float* b1 = (const float*)d_in[5];
    const float* W2 = (const float*)d_in[6];
    const float* b2 = (const float*)d_in[7];
    const float* W3 = (const float*)d_in[8];
    const float* b3 = (const float*)d_in[9];
    const int* src = ei;
    const int* dst = ei + N_EDGES;

    // ws layout (16B-aligned):
    __half* A      = (__half*)d_ws;                        // 50000*128 f16
    __half* Hh     = A + (size_t)N_NODES * 128;            // 50000*128 f16
    __half* WT     = Hh + (size_t)N_NODES * 128;           // 3*128*128 f16
    float*  H16    = (float*)(WT + 3 * 128 * 128);         // 50000*16 f32
    float*  dinv   = H16 + (size_t)N_NODES * 16;           // 50000
    unsigned* packed = (unsigned*)(dinv + N_NODES);        // 50000
    int*    gcur   = (int*)(packed + N_NODES);             // 1024 (NB padded)
    int*    eidx   = gcur + 1024;                          // NB*CAP
    unsigned* arena = (unsigned*)(eidx + NB * CAP);        // NB*CAP

    // ---- CSR build + prep (every call; ws is re-poisoned) ----
    (void)hipMemsetAsync(gcur, 0, 1024 * sizeof(int), stream);
    k_bucket<<<BUCKET_BLOCKS, 256, 0, stream>>>(src, dst, gcur, arena);
    k_fill3prep<<<FILL_GRID, 256, 0, stream>>>(arena, gcur, packed, dinv,
                                               eidx, x, A, W0, W1, W2, WT);

    const int GB = (N_NODES + 63) / 64;  // mfma gemm blocks (64 rows each)
    // ---- layer 0 ----
    k_gemm_mfma<<<GB, 256, 0, stream>>>(A, WT, dinv, Hh);
    k_gather_h<false, __half><<<N_NODES * 16 / 256, 256, 0, stream>>>(
        packed, eidx, Hh, dinv, b0, A);
    // ---- layer 1 ----
    k_gemm_mfma<<<GB, 256, 0, stream>>>(A, WT + 128 * 128, dinv, Hh);
    k_gather_h<false, __half><<<N_NODES * 16 / 256, 256, 0, stream>>>(
        packed, eidx, Hh, dinv, b1, A);
    // ---- layer 2 ----
    k_gemm_mfma<<<GB, 256, 0, stream>>>(A, WT + 2 * 128 * 128, dinv, Hh);
    k_gather_h<false, __half><<<N_NODES * 16 / 256, 256, 0, stream>>>(
        packed, eidx, Hh, dinv, b2, A);
    // ---- layer 3 (128 -> 16, tanh) ----
    k_gemm16<<<N_NODES * 16 / 256, 256, 0, stream>>>(A, W3, dinv, H16);
    k_gather4<true><<<(N_NODES * 4 + 255) / 256, 256, 0, stream>>>(
        packed, eidx, H16, dinv, b3, (float*)d_out);
}

// Round 12
// 311.623 us; speedup vs baseline: 14.4582x; 1.0201x over previous
//
#include <hip/hip_runtime.h>
#include <hip/hip_fp16.h>
#include <math.h>

#define N_NODES 50000
#define N_EDGES 800000
#define NB 782            // ceil(50000/64) buckets of 64 dst nodes
#define CH 4096           // edges per k_bucket block
#define CAP 2048          // arena slots per bucket (Poisson(1024) -> 2x slack)
#define BUCKET_BLOCKS 196 // ceil(800000/4096)
#define CAST_BLOCKS 6250  // N_NODES*128/4/256
#define PREPW_BLOCKS 192  // 3 * 16384/256
#define FILL_GRID (NB + CAST_BLOCKS + PREPW_BLOCKS)

typedef _Float16 half8 __attribute__((ext_vector_type(8)));
typedef float floatx4 __attribute__((ext_vector_type(4)));
typedef unsigned uintx4 __attribute__((ext_vector_type(4)));

// ---- pass 1: LDS-staged bucket scatter into padded arena ------------------
// bucket = dst>>6, segment base = b*CAP, edge packed (dst<<16)|src.
__global__ __launch_bounds__(256) void k_bucket(const int* __restrict__ src,
                                                const int* __restrict__ dst,
                                                int* __restrict__ gcur,
                                                unsigned* __restrict__ arena) {
    __shared__ int cntA[NB];
    __shared__ int lofs[NB];
    __shared__ int gbase[NB];
    __shared__ int part[256];
    __shared__ unsigned buf[CH];
    const int t = threadIdx.x;
    const int ebase = blockIdx.x * CH;
    const int chunkN = min(CH, N_EDGES - ebase);

    for (int i = t; i < NB; i += 256) cntA[i] = 0;
    __syncthreads();
    for (int i = t; i < chunkN; i += 256)
        atomicAdd(&cntA[dst[ebase + i] >> 6], 1);
    __syncthreads();
    // exclusive scan of cntA -> lofs; reserve arena sub-ranges via gcur
    int c[4];
    int s = 0;
#pragma unroll
    for (int q = 0; q < 4; ++q) {
        int idx = t * 4 + q;
        c[q] = (idx < NB) ? cntA[idx] : 0;
        s += c[q];
    }
    part[t] = s;
    __syncthreads();
    for (int d = 1; d < 256; d <<= 1) {
        int u = (t >= d) ? part[t - d] : 0;
        __syncthreads();
        part[t] += u;
        __syncthreads();
    }
    int run = (t > 0) ? part[t - 1] : 0;
#pragma unroll
    for (int q = 0; q < 4; ++q) {
        int idx = t * 4 + q;
        if (idx < NB) {
            lofs[idx] = run;
            run += c[q];
            gbase[idx] = (c[q] > 0) ? atomicAdd(&gcur[idx], c[q]) : 0;
            cntA[idx] = 0;  // reuse as placement cursor
        }
    }
    __syncthreads();
    // place packed edges into LDS ordered by bucket
    for (int i = t; i < chunkN; i += 256) {
        int d = dst[ebase + i];
        int sv = src[ebase + i];
        int b = d >> 6;
        int pos = atomicAdd(&cntA[b], 1);
        buf[lofs[b] + pos] = ((unsigned)d << 16) | (unsigned)sv;
    }
    __syncthreads();
    // flush contiguous per-bucket bursts into the padded arena
    for (int i = t; i < chunkN; i += 256) {
        unsigned v = buf[i];
        int b = (int)(v >> 16) >> 6;
        int q = i - lofs[b];
        int p = gbase[b] + q;
        if (p < CAP) arena[((size_t)b << 11) + p] = v;
    }
}

// ---- pass 2 (fused): bucket finalize | x->fp16 cast | W->fp16 W^T ---------
// W^T is stored FEATURE-PERMUTED for the mfma epilogue: position n'=nt*16+m
// holds logical column m*8+nt, so each lane's 8 outputs are contiguous.
__global__ __launch_bounds__(256) void k_fill3prep(
    const unsigned* __restrict__ arena, const int* __restrict__ gcur,
    unsigned* __restrict__ packed, float* __restrict__ dinv,
    int* __restrict__ eidx, const float* __restrict__ x,
    __half* __restrict__ xh, const float* __restrict__ W0,
    const float* __restrict__ W1, const float* __restrict__ W2,
    __half* __restrict__ WT) {
    const int t = threadIdx.x;
    if (blockIdx.x < NB) {
        const int b = blockIdx.x;
        __shared__ int cnt64[64];
        __shared__ int cur64[64];
        if (t < 64) cnt64[t] = 0;
        __syncthreads();
        const int seglen = min(gcur[b], CAP);
        const unsigned* seg = arena + ((size_t)b << 11);
        for (int i = t; i < seglen; i += 256)
            atomicAdd(&cnt64[(seg[i] >> 16) & 63], 1);
        __syncthreads();
        if (t < 64) {  // one wave: prefix scan of 64 counts
            int v = cnt64[t];
            int p = v;
#pragma unroll
            for (int d = 1; d < 64; d <<= 1) {
                int u = __shfl_up(p, d, 64);
                if (t >= d) p += u;
            }
            int excl = p - v;
            int node = b * 64 + t;
            if (node < N_NODES) {
                packed[node] =
                    ((unsigned)((b << 11) + excl) << 11) | (unsigned)v;
                dinv[node] = rsqrtf((float)v + 2.0f);  // improved: +2
            }
            cur64[t] = excl;
        }
        __syncthreads();
        const int base = b << 11;
        for (int i = t; i < seglen; i += 256) {
            unsigned v = seg[i];
            int d = (int)(v >> 16) & 63;
            int pos = atomicAdd(&cur64[d], 1);
            eidx[base + pos] = (int)(v & 0xFFFFu);
        }
    } else if (blockIdx.x < NB + CAST_BLOCKS) {
        int i = (blockIdx.x - NB) * 256 + t;  // float4-granular, exact
        float4 v = *(const float4*)&x[(size_t)i * 4];
        union { ushort4 u; __half h[4]; } p;
        p.h[0] = __float2half(v.x); p.h[1] = __float2half(v.y);
        p.h[2] = __float2half(v.z); p.h[3] = __float2half(v.w);
        *(ushort4*)&xh[(size_t)i * 4] = p.u;
    } else {
        int idx = blockIdx.x - NB - CAST_BLOCKS;  // 0..191
        int which = idx >> 6;
        const float* W = (which == 0) ? W0 : (which == 1) ? W1 : W2;
        int i = (idx & 63) * 256 + t;  // 16384 per matrix: i = k*128 + n
        int k = i >> 7, n = i & 127;
        int np = ((n & 7) << 4) + (n >> 3);  // inverse of perm(n')=(n'&15)*8+(n'>>4)
        WT[which * 128 * 128 + np * 128 + k] = __float2half(W[i]);
    }
}

// ====== MFMA GEMM: hs = fp16((Ah @ W) * dinv[row]) via permuted W^T ========
// Lane (m,quad), call nt computes cols m*8+nt -> uintx4 row-segment stores.
__global__ __launch_bounds__(256) void k_gemm_mfma(const __half* __restrict__ Ah,
                                                   const __half* __restrict__ WT,
                                                   const float* __restrict__ dinv,
                                                   __half* __restrict__ hs) {
    const int tid = threadIdx.x;
    const int wave = tid >> 6;
    const int lane = tid & 63;
    const int m = lane & 15;
    const int quad = lane >> 4;
    const int rowA = blockIdx.x * 64 + wave * 16 + m;
    const int rA = (rowA < N_NODES) ? rowA : 0;
    const __half* arow = Ah + (size_t)rA * 128 + quad * 8;

    floatx4 acc[8] = {};
#pragma unroll
    for (int kb = 0; kb < 4; ++kb) {
        half8 af = __builtin_nontemporal_load((const half8*)(arow + kb * 32));
#pragma unroll
        for (int nt = 0; nt < 8; ++nt) {
            half8 bf = *(const half8*)(WT + (size_t)(nt * 16 + m) * 128 +
                                       kb * 32 + quad * 8);
            acc[nt] = __builtin_amdgcn_mfma_f32_16x16x32_f16(af, bf, acc[nt],
                                                             0, 0, 0);
        }
    }
    // C/D: physical col of (lane m, call nt) = m*8+nt; row = quad*4 + reg
    const int rb = blockIdx.x * 64 + wave * 16 + quad * 4;
#pragma unroll
    for (int r = 0; r < 4; ++r) {
        int row = rb + r;
        if (row < N_NODES) {
            float dv = dinv[row];
            union { uintx4 u; __half h[8]; } pk;
#pragma unroll
            for (int nt = 0; nt < 8; ++nt)
                pk.h[nt] = __float2half(acc[nt][r] * dv);
            *(uintx4*)(hs + (size_t)row * 128 + m * 8) = pk.u;
        }
    }
}

// ====== fused aggregate + epilogue, fp16 H, F=128 ======
__device__ __forceinline__ void acc8(const __half* p, float* acc) {
    union { uint4 u; __half2 h2[4]; } t;
    t.u = *(const uint4*)p;
#pragma unroll
    for (int q = 0; q < 4; ++q) {
        float2 v = __half22float2(t.h2[q]);
        acc[2 * q] += v.x;
        acc[2 * q + 1] += v.y;
    }
}
__device__ __forceinline__ void store8_nt(__half* p, const float* o) {
    union { uintx4 u; __half h[8]; } c;
#pragma unroll
    for (int j = 0; j < 8; ++j) c.h[j] = __float2half(o[j]);
    __builtin_nontemporal_store(c.u, (uintx4*)p);
}

// gather core: acc[8] = 2*hs[r] + sum_neighbors hs[s]  (slice f = l*8)
__device__ __forceinline__ void gather_core(const unsigned* packed,
                                            const int* eidx,
                                            const __half* hs, int r, int l,
                                            int f, float* acc) {
    {
        union { uint4 u; __half2 h2[4]; } p;
        p.u = *(const uint4*)&hs[(size_t)r * 128 + f];
#pragma unroll
        for (int q = 0; q < 4; ++q) {
            float2 v = __half22float2(p.h2[q]);
            acc[2 * q] = 2.f * v.x;
            acc[2 * q + 1] = 2.f * v.y;
        }
    }
    unsigned pk = packed[r];
    int i = (int)(pk >> 11);
    int end = i + (int)(pk & 2047u);
    for (; i + 16 <= end; i += 16) {
        int my = __builtin_nontemporal_load(&eidx[i + l]);
#pragma unroll
        for (int j = 0; j < 16; ++j) {
            int s = __shfl(my, j, 16);
            acc8(&hs[(size_t)s * 128 + f], acc);
        }
    }
    if (i < end) {
        int n = end - i;
        int my = (l < n) ? eidx[i + l] : 0;
        for (int j = 0; j < n; ++j) {
            int s = __shfl(my, j, 16);
            acc8(&hs[(size_t)s * 128 + f], acc);
        }
    }
}

// layers 0/1: out = fp16(relu(dinv*agg + b))
__global__ __launch_bounds__(256) void k_gather_h(const unsigned* __restrict__ packed,
                                                  const int* __restrict__ eidx,
                                                  const __half* __restrict__ hs,
                                                  const float* __restrict__ dinv,
                                                  const float* __restrict__ bias,
                                                  __half* __restrict__ out) {
    int tid = blockIdx.x * 256 + threadIdx.x;  // grid exact: 3125 blocks
    int r = tid >> 4;
    int l = tid & 15;
    int f = l * 8;
    float acc[8];
    gather_core(packed, eidx, hs, r, l, f, acc);
    float dv = dinv[r];
    float o[8];
#pragma unroll
    for (int j = 0; j < 8; ++j)
        o[j] = fmaxf(dv * acc[j] + bias[f + j], 0.f);
    store8_nt(out + (size_t)r * 128 + f, o);
}

// layer 2 + fused 128->16 projection: H16[r][l] = (relu_row @ W3)[l] * dinv[r]
__global__ __launch_bounds__(256) void k_gather_fuse16(
    const unsigned* __restrict__ packed, const int* __restrict__ eidx,
    const __half* __restrict__ hs, const float* __restrict__ dinv,
    const float* __restrict__ bias, const float* __restrict__ W3,
    float* __restrict__ h16) {
    __shared__ float W3l[128 * 16];
    for (int i = threadIdx.x; i < 128 * 16; i += 256) W3l[i] = W3[i];
    __syncthreads();
    int tid = blockIdx.x * 256 + threadIdx.x;  // grid exact: 3125 blocks
    int r = tid >> 4;
    int l = tid & 15;
    int f = l * 8;
    float acc[8];
    gather_core(packed, eidx, hs, r, l, f, acc);
    float dv = dinv[r];
    float o[8];
#pragma unroll
    for (int j = 0; j < 8; ++j)
        o[j] = fmaxf(dv * acc[j] + bias[f + j], 0.f);
    // shfl-exchange projection: lane l accumulates output class l
    float cls = 0.f;
#pragma unroll
    for (int j = 0; j < 16; ++j) {
#pragma unroll
        for (int q = 0; q < 8; ++q) {
            float a = __shfl(o[q], j, 16);
            cls += a * W3l[(j * 8 + q) * 16 + l];
        }
    }
    h16[(size_t)r * 16 + l] = cls * dv;
}

// ====== fp32 gather for the last (F=16) layer ======
__global__ __launch_bounds__(256) void k_gather4(const unsigned* __restrict__ packed,
                                                 const int* __restrict__ eidx,
                                                 const float* __restrict__ hs,
                                                 const float* __restrict__ dinv,
                                                 const float* __restrict__ bias,
                                                 float* __restrict__ out) {
    int tid = blockIdx.x * 256 + threadIdx.x;
    int r = tid >> 2;
    if (r >= N_NODES) return;
    int l = tid & 3;
    int f = l * 4;
    float4 h = *(const float4*)&hs[(size_t)r * 16 + f];
    float ax = 2.f * h.x, ay = 2.f * h.y, az = 2.f * h.z, aw = 2.f * h.w;
    unsigned pk = packed[r];
    int i = (int)(pk >> 11);
    int end = i + (int)(pk & 2047u);
    for (; i + 4 <= end; i += 4) {
        int my = eidx[i + l];
#pragma unroll
        for (int j = 0; j < 4; ++j) {
            int s = __shfl(my, j, 4);
            float4 v = *(const float4*)&hs[(size_t)s * 16 + f];
            ax += v.x; ay += v.y; az += v.z; aw += v.w;
        }
    }
    if (i < end) {
        int n = end - i;
        int my = (l < n) ? eidx[i + l] : 0;
        for (int j = 0; j < n; ++j) {
            int s = __shfl(my, j, 4);
            float4 v = *(const float4*)&hs[(size_t)s * 16 + f];
            ax += v.x; ay += v.y; az += v.z; aw += v.w;
        }
    }
    float dv = dinv[r];
    float v0 = tanhf(dv * ax + bias[f + 0]);
    float v1 = tanhf(dv * ay + bias[f + 1]);
    float v2 = tanhf(dv * az + bias[f + 2]);
    float v3 = tanhf(dv * aw + bias[f + 3]);
    floatx4 o = {v0, v1, v2, v3};
    __builtin_nontemporal_store(o, (floatx4*)&out[(size_t)r * 16 + f]);
}

extern "C" void kernel_launch(void* const* d_in, const int* in_sizes, int n_in,
                              void* d_out, int out_size, void* d_ws, size_t ws_size,
                              hipStream_t stream) {
    const float* x  = (const float*)d_in[0];
    const int* ei   = (const int*)d_in[1];
    const float* W0 = (const float*)d_in[2];
    const float* b0 = (const float*)d_in[3];
    const float* W1 = (const float*)d_in[4];
    const float* b1 = (const float*)d_in[5];
    const float* W2 = (const float*)d_in[6];
    const float* b2 = (const float*)d_in[7];
    const float* W3 = (const float*)d_in[8];
    const float* b3 = (const float*)d_in[9];
    const int* src = ei;
    const int* dst = ei + N_EDGES;

    // ws layout (16B-aligned):
    __half* A      = (__half*)d_ws;                        // 50000*128 f16
    __half* Hh     = A + (size_t)N_NODES * 128;            // 50000*128 f16
    __half* WT     = Hh + (size_t)N_NODES * 128;           // 3*128*128 f16
    float*  H16    = (float*)(WT + 3 * 128 * 128);         // 50000*16 f32
    float*  dinv   = H16 + (size_t)N_NODES * 16;           // 50000
    unsigned* packed = (unsigned*)(dinv + N_NODES);        // 50000
    int*    gcur   = (int*)(packed + N_NODES);             // 1024 (NB padded)
    int*    eidx   = gcur + 1024;                          // NB*CAP
    unsigned* arena = (unsigned*)(eidx + NB * CAP);        // NB*CAP

    // ---- CSR build + prep (every call; ws is re-poisoned) ----
    (void)hipMemsetAsync(gcur, 0, 1024 * sizeof(int), stream);
    k_bucket<<<BUCKET_BLOCKS, 256, 0, stream>>>(src, dst, gcur, arena);
    k_fill3prep<<<FILL_GRID, 256, 0, stream>>>(arena, gcur, packed, dinv,
                                               eidx, x, A, W0, W1, W2, WT);

    const int GB = (N_NODES + 63) / 64;  // mfma gemm blocks (64 rows each)
    // ---- layer 0 ----
    k_gemm_mfma<<<GB, 256, 0, stream>>>(A, WT, dinv, Hh);
    k_gather_h<<<N_NODES * 16 / 256, 256, 0, stream>>>(packed, eidx, Hh,
                                                       dinv, b0, A);
    // ---- layer 1 ----
    k_gemm_mfma<<<GB, 256, 0, stream>>>(A, WT + 128 * 128, dinv, Hh);
    k_gather_h<<<N_NODES * 16 / 256, 256, 0, stream>>>(packed, eidx, Hh,
                                                       dinv, b1, A);
    // ---- layer 2 (+ fused 128->16 projection) ----
    k_gemm_mfma<<<GB, 256, 0, stream>>>(A, WT + 2 * 128 * 128, dinv, Hh);
    k_gather_fuse16<<<N_NODES * 16 / 256, 256, 0, stream>>>(
        packed, eidx, Hh, dinv, b2, W3, H16);
    // ---- layer 3 (aggregate in class space, tanh) ----
    k_gather4<<<(N_NODES * 4 + 255) / 256, 256, 0, stream>>>(
        packed, eidx, H16, dinv, b3, (float*)d_out);
}